// Round 13
// baseline (410.518 us; speedup 1.0000x reference)
//
#include <hip/hip_runtime.h>
#include <stdint.h>
#include <math.h>

typedef __attribute__((ext_vector_type(8))) short bf16x8;
typedef __attribute__((ext_vector_type(4))) float f32x4;

__device__ __forceinline__ ushort f2bf(float f) {      // RTNE, finite inputs
    uint32_t u = __float_as_uint(f);
    u += 0x7fffu + ((u >> 16) & 1u);
    return (ushort)(u >> 16);
}

// ---------------- Threefry-2x32 (JAX-exact, partitionable mode) ----------------
__device__ __forceinline__ uint32_t rotl32(uint32_t v, int r) {
    return (v << r) | (v >> (32 - r));
}

__device__ __forceinline__ void threefry(uint32_t k0, uint32_t k1,
                                         uint32_t c0, uint32_t c1,
                                         uint32_t& o0, uint32_t& o1) {
    uint32_t ks2 = k0 ^ k1 ^ 0x1BD11BDAu;
    uint32_t x0 = c0 + k0, x1 = c1 + k1;
    x0 += x1; x1 = rotl32(x1, 13); x1 ^= x0;
    x0 += x1; x1 = rotl32(x1, 15); x1 ^= x0;
    x0 += x1; x1 = rotl32(x1, 26); x1 ^= x0;
    x0 += x1; x1 = rotl32(x1,  6); x1 ^= x0;
    x0 += k1;  x1 += ks2 + 1u;
    x0 += x1; x1 = rotl32(x1, 17); x1 ^= x0;
    x0 += x1; x1 = rotl32(x1, 29); x1 ^= x0;
    x0 += x1; x1 = rotl32(x1, 16); x1 ^= x0;
    x0 += x1; x1 = rotl32(x1, 24); x1 ^= x0;
    x0 += ks2; x1 += k0 + 2u;
    x0 += x1; x1 = rotl32(x1, 13); x1 ^= x0;
    x0 += x1; x1 = rotl32(x1, 15); x1 ^= x0;
    x0 += x1; x1 = rotl32(x1, 26); x1 ^= x0;
    x0 += x1; x1 = rotl32(x1,  6); x1 ^= x0;
    x0 += k0;  x1 += k1 + 3u;
    x0 += x1; x1 = rotl32(x1, 17); x1 ^= x0;
    x0 += x1; x1 = rotl32(x1, 29); x1 ^= x0;
    x0 += x1; x1 = rotl32(x1, 16); x1 ^= x0;
    x0 += x1; x1 = rotl32(x1, 24); x1 ^= x0;
    x0 += k1;  x1 += ks2 + 4u;
    x0 += x1; x1 = rotl32(x1, 13); x1 ^= x0;
    x0 += x1; x1 = rotl32(x1, 15); x1 ^= x0;
    x0 += x1; x1 = rotl32(x1, 26); x1 ^= x0;
    x0 += x1; x1 = rotl32(x1,  6); x1 ^= x0;
    x0 += ks2; x1 += k0 + 5u;
    o0 = x0; o1 = x1;
}

__device__ __forceinline__ uint32_t rbits32(uint32_t k0, uint32_t k1, uint32_t idx) {
    uint32_t o0, o1;
    threefry(k0, k1, 0u, idx, o0, o1);
    return o0 ^ o1;
}

__device__ __forceinline__ float u01_from_bits(uint32_t bits) {
    return __uint_as_float((bits >> 9) | 0x3f800000u) - 1.0f;
}

__device__ float erfinv_xla(float x) {
    #pragma clang fp contract(off)
    float w = -log1pf(-x * x);
    float p;
    if (w < 5.0f) {
        w = w - 2.5f;
        p = 2.81022636e-08f;
        p = 3.43273939e-07f + p * w;
        p = -3.5233877e-06f + p * w;
        p = -4.39150654e-06f + p * w;
        p = 0.00021858087f + p * w;
        p = -0.00125372503f + p * w;
        p = -0.00417768164f + p * w;
        p = 0.246640727f + p * w;
        p = 1.50140941f + p * w;
    } else {
        w = sqrtf(w) - 3.0f;
        p = -0.000200214257f;
        p = 0.000100950558f + p * w;
        p = 0.00134934322f + p * w;
        p = -0.00367342844f + p * w;
        p = 0.00573950773f + p * w;
        p = -0.0076224613f + p * w;
        p = 0.00943887047f + p * w;
        p = 1.00167406f + p * w;
        p = 2.83297682f + p * w;
    }
    return p * x;
}

// ---------------- workspace layout (float offsets) ----------------
#define P_OFF      0           // 8192*12
#define NK_OFF     98304       // 4 u32 (16 f reserved)
#define W2GT_OFF   98320       // 64*296 bf16 = 9472 f
#define WFB_OFF    107792      // 512*3136 bf16 = 802816 f
#define WP1B_OFF   910608      // 512*512 bf16 = 131072 f
#define WP2B_OFF   1041680     // 128*512 bf16 = 32768 f
#define AUG_OFF    1074448     // 4096*784 f32 (P1 bf16 aliases this region)
#define PL2_OFF    4285712     // 4096*3136 bf16 = 6422528 f
#define H_OFF      10708240    // 4096*512 bf16 = 1048576 f
// end = 11,756,816 floats = 47.0 MB

// ---------------- kernels ----------------
__global__ void param_kernel(float* __restrict__ P, uint32_t* __restrict__ NK) {
    #pragma clang fp contract(off)
    int gid = blockIdx.x * blockDim.x + threadIdx.x;
    if (gid >= 8192) return;
    int v = gid >> 12;
    int i = gid & 4095;

    uint32_t kv0, kv1;
    threefry(0u, 42u, 0u, (uint32_t)v, kv0, kv1);

    uint32_t sk0[11], sk1[11];
    #pragma unroll
    for (int j = 0; j < 11; ++j) threefry(kv0, kv1, 0u, (uint32_t)j, sk0[j], sk1[j]);

    float u[10];
    #pragma unroll
    for (int j = 0; j < 10; ++j) u[j] = u01_from_bits(rbits32(sk0[j], sk1[j], (uint32_t)i));

    float crop = floorf(28.0f * (0.7f + 0.3f * u[0]));
    float top  = floorf((28.0f - crop) * u[1]);
    float left = floorf((28.0f - crop) * u[2]);
    float flip = (u[3] < 0.5f) ? 1.0f : 0.0f;
    float rot  = (u[4] < 0.8f) ? 1.0f : 0.0f;
    float rad  = ((20.0f * u[5] - 10.0f) * 3.14159274101257324f) / 180.0f;
    float cj   = (u[6] < 0.8f) ? 1.0f : 0.0f;
    float bb   = 0.2f * u[7] - 0.1f;
    float cc   = 0.8f + 0.4f * u[8];
    float na   = (u[9] < 0.5f) ? 1.0f : 0.0f;

    float* p = P + gid * 12;
    p[0] = crop; p[1] = top; p[2] = left; p[3] = flip; p[4] = rot;
    p[5] = rad;  p[6] = cj;  p[7] = bb;   p[8] = cc;   p[9] = na;
    p[10] = cosf(rad); p[11] = sinf(rad);   // hoisted (identical bits to in-kernel cosf/sinf)

    if (i == 0) { NK[v * 2] = sk0[10]; NK[v * 2 + 1] = sk1[10]; }
}

// W2 (64,32,3,3) -> W2gT[oc][k=(ky*3+kx)*32+ic], padded row stride 296, bf16
__global__ void wprep_w2(const float* __restrict__ W2, ushort* __restrict__ W2gT) {
    int idx = blockIdx.x * 256 + threadIdx.x;
    if (idx >= 64 * 296) return;
    int oc = idx / 296, k = idx % 296;
    float v = 0.0f;
    if (k < 288) {
        int s = k >> 5, ic = k & 31;
        int ky = s / 3, kx = s % 3;
        v = W2[((oc * 32 + ic) * 3 + ky) * 3 + kx];
    }
    W2gT[idx] = f2bf(v);
}

// Wf (512, 3136=oc*49+pos) -> WfB[n][k'=pos*64+oc] bf16
__global__ void wprep_wf(const float* __restrict__ Wf, ushort* __restrict__ WfB) {
    int idx = blockIdx.x * 256 + threadIdx.x;
    if (idx >= 512 * 3136) return;
    int n = idx / 3136, kp = idx % 3136;
    int pos = kp >> 6, oc = kp & 63;
    WfB[idx] = f2bf(Wf[n * 3136 + oc * 49 + pos]);
}

__global__ void wprep_cast(const float* __restrict__ src, ushort* __restrict__ dst, int n) {
    int idx = blockIdx.x * 256 + threadIdx.x;
    if (idx < n) dst[idx] = f2bf(src[idx]);
}

// Block-per-image augment (R6/R9-proven structure + coord table + hoisted trig)
__global__ __launch_bounds__(256) void augment_kernel(const float* __restrict__ x,
                                                      const float* __restrict__ P,
                                                      const uint32_t* __restrict__ NK,
                                                      float* __restrict__ AUG, int v) {
    #pragma clang fp contract(off)
    int i = blockIdx.x;                 // 0..4095
    int r = v * 4096 + i;
    int t = threadIdx.x;
    __shared__ float img[784];
    __shared__ float s1[784];
    __shared__ float srctab[28];        // clamp(j*crop/28-0.5, 0, crop-1), shared by y & x

    const float* p = P + r * 12;
    float crop = p[0], top = p[1], left = p[2];
    int flip = (p[3] != 0.0f);
    int rot  = (p[4] != 0.0f);
    int cj = (p[6] != 0.0f);
    float bb = p[7], cc = p[8];
    int na = (p[9] != 0.0f);
    float cs = p[10], sn = p[11];
    uint32_t nk0 = NK[v * 2], nk1 = NK[v * 2 + 1];

    for (int q = t; q < 784; q += 256) img[q] = x[i * 784 + q];
    if (t < 28) {
        float j = (float)t + 0.5f;
        float s = j * crop / 28.0f - 0.5f;
        srctab[t] = fminf(fmaxf(s, 0.0f), crop - 1.0f);
    }
    __syncthreads();

    for (int q = t; q < 784; q += 256) {
        int py = q / 28, px = q - (q / 28) * 28;
        int sxcol = flip ? (27 - px) : px;
        float yy = srctab[py] + top;
        float xx = srctab[sxcol] + left;
        float y0f = floorf(yy), x0f = floorf(xx);
        float wy = yy - y0f, wx = xx - x0f;
        int y0 = (int)y0f, x0 = (int)x0f;

        int yc0 = min(max(y0, 0), 27),     xc0 = min(max(x0, 0), 27);
        int yc1 = min(max(y0 + 1, 0), 27), xc1 = min(max(x0 + 1, 0), 27);
        float g00 = img[yc0 * 28 + xc0];
        float g01 = img[yc0 * 28 + xc1];
        float g10 = img[yc1 * 28 + xc0];
        float g11 = img[yc1 * 28 + xc1];
        float val = g00 * (1.0f - wy) * (1.0f - wx) + g01 * (1.0f - wy) * wx
                  + g10 * wy * (1.0f - wx) + g11 * wy * wx;
        s1[q] = val;
    }
    __syncthreads();

    for (int q = t; q < 784; q += 256) {
        int py = q / 28, px = q - (q / 28) * 28;
        float val;
        if (rot) {
            float Yn = (2.0f * (float)py + 1.0f) / 28.0f - 1.0f;
            float Xn = (2.0f * (float)px + 1.0f) / 28.0f - 1.0f;
            float xs = cs * Xn - sn * Yn;
            float ys = sn * Xn + cs * Yn;
            float ix = ((xs + 1.0f) * 28.0f - 1.0f) / 2.0f;
            float iy = ((ys + 1.0f) * 28.0f - 1.0f) / 2.0f;
            float y0f = floorf(iy), x0f = floorf(ix);
            float wy = iy - y0f, wx = ix - x0f;
            int y0 = (int)y0f, x0 = (int)x0f;
            float g[2][2];
            #pragma unroll
            for (int dy = 0; dy < 2; ++dy) {
                #pragma unroll
                for (int dx = 0; dx < 2; ++dx) {
                    int yi = y0 + dy, xi = x0 + dx;
                    int yc = min(max(yi, 0), 27), xc = min(max(xi, 0), 27);
                    float vv = s1[yc * 28 + xc];
                    float valid = (yi >= 0 && yi < 28 && xi >= 0 && xi < 28) ? 1.0f : 0.0f;
                    g[dy][dx] = vv * valid;
                }
            }
            val = g[0][0] * (1.0f - wy) * (1.0f - wx) + g[0][1] * (1.0f - wy) * wx
                + g[1][0] * wy * (1.0f - wx) + g[1][1] * wy * wx;
        } else {
            val = s1[q];
        }

        if (cj) {
            float vc = fminf(fmaxf(val + bb, 0.0f), 1.0f);
            val = fminf(fmaxf((vc - 0.5f) * cc + 0.5f, 0.0f), 1.0f);
        }

        if (na) {
            int idx = i * 784 + q;
            uint32_t bits = rbits32(nk0, nk1, (uint32_t)idx);
            float f = u01_from_bits(bits);
            const float lo = -0.99999994f;
            float uu = f * 2.0f + lo;
            uu = fmaxf(lo, uu);
            float n = 1.4142135623730951f * erfinv_xla(uu);
            val = fminf(fmaxf(val + 0.05f * n, 0.0f), 1.0f);
        }

        AUG[i * 784 + q] = (val - 0.5f) / 0.5f;
    }
}

// conv1 via MFMA (pool-ordered im2col, thread-per-pooled-position fill) + conv2
// via MFMA (wave-per-oc-tile). A1 and pl1p ALIAS one LDS buffer; phase-2 outputs
// ride in registers (statically indexed) across the handoff.
__global__ __launch_bounds__(256) void conv12_kernel(
        const float* __restrict__ AUG,
        const float* __restrict__ W1, const float* __restrict__ b1,
        const ushort* __restrict__ W2gT, const float* __restrict__ b2,
        ushort* __restrict__ PL2) {
    int i = blockIdx.x, t = threadIdx.x;
    __shared__ __align__(16) ushort buf[12576];           // 25152 B: A1, then pl1p
    __shared__ __align__(16) ushort w1sT[32 * 32];        // 2048 B  [oc][k]
    ushort* A1   = buf;                                   // [784 rows][16]
    ushort* pl1p = buf;                                   // [16][18][40] = 11520 ushorts

    // phase 0: build w1sT (bf16, K-padded with zeros)
    {
        int q0 = t * 4;
        #pragma unroll
        for (int j = 0; j < 4; ++j) {
            int q = q0 + j;                  // oc*32 + k
            int oc = q >> 5, k = q & 31;
            w1sT[q] = (k < 9) ? f2bf(W1[oc * 9 + k]) : (ushort)0;
        }
    }

    // phase 1: im2col, ONE THREAD PER POOLED POSITION (t<196)
    const float* Ai = AUG + (size_t)i * 784;
    if (t < 196) {
        int py = t / 14, px = t - (t / 14) * 14;
        int ybase = 2 * py - 1, xbase = 2 * px - 1;
        uint32_t u[4][4];
        #pragma unroll
        for (int ry = 0; ry < 4; ++ry) {
            int yy = ybase + ry;
            bool yok = (unsigned)yy < 28u;
            const float* rowp = Ai + yy * 28;
            #pragma unroll
            for (int rx = 0; rx < 4; ++rx) {
                int xx = xbase + rx;
                float vv = (yok && (unsigned)xx < 28u) ? rowp[xx] : 0.0f;
                u[ry][rx] = (uint32_t)f2bf(vv);
            }
        }
        #pragma unroll
        for (int w = 0; w < 4; ++w) {
            int dy = w >> 1, dx = w & 1;
            uint4 W0, W1v;
            W0.x = u[dy][dx]     | (u[dy][dx + 1] << 16);
            W0.y = u[dy][dx + 2] | (u[dy + 1][dx] << 16);
            W0.z = u[dy + 1][dx + 1] | (u[dy + 1][dx + 2] << 16);
            W0.w = u[dy + 2][dx]     | (u[dy + 2][dx + 1] << 16);
            W1v.x = u[dy + 2][dx + 2];
            W1v.y = 0; W1v.z = 0; W1v.w = 0;
            ((uint4*)A1)[(t * 4 + w) * 2]     = W0;
            ((uint4*)A1)[(t * 4 + w) * 2 + 1] = W1v;
        }
    }
    __syncthreads();

    int l = t & 63, wv = t >> 6;
    int lr = l & 15, lg = l >> 4;

    // phase 2a: conv1 MFMA -> pooled values in REGISTERS (static indices only)
    float m0r[13], m1r[13];
    {
        bf16x8 bA = *(const bf16x8*)(w1sT + lr * 32 + lg * 8);          // oc = lr
        bf16x8 bB = *(const bf16x8*)(w1sT + (16 + lr) * 32 + lg * 8);   // oc = 16+lr
        #pragma unroll
        for (int it = 0; it < 13; ++it) {
            int tt = wv + it * 4;
            if (tt < 49) {                       // wave-uniform guard
                bf16x8 af = *(const bf16x8*)(A1 + (tt * 16 + lr) * 16 + lg * 8);
                f32x4 a0 = {0.0f, 0.0f, 0.0f, 0.0f};
                f32x4 a1acc = {0.0f, 0.0f, 0.0f, 0.0f};
                a0    = __builtin_amdgcn_mfma_f32_16x16x32_bf16(af, bA, a0, 0, 0, 0);
                a1acc = __builtin_amdgcn_mfma_f32_16x16x32_bf16(af, bB, a1acc, 0, 0, 0);
                m0r[it] = fmaxf(fmaxf(a0[0], a0[1]), fmaxf(a0[2], a0[3]));
                m1r[it] = fmaxf(fmaxf(a1acc[0], a1acc[1]), fmaxf(a1acc[2], a1acc[3]));
            }
        }
    }
    __syncthreads();                             // all A1 reads complete

    // phase 2b: zero pl1p (borders + ic-pad) in A1's storage
    for (int q = t; q < 1440; q += 256) ((uint4*)pl1p)[q] = uint4{0, 0, 0, 0};
    __syncthreads();

    // phase 2c: scatter pooled registers -> pl1p
    {
        float bia0 = b1[lr], bia1 = b1[16 + lr];
        #pragma unroll
        for (int it = 0; it < 13; ++it) {
            int tt = wv + it * 4;
            if (tt < 49) {
                int pidx = tt * 4 + lg;
                int py = pidx / 14, px = pidx - py * 14;
                int base = ((py + 1) * 18 + (px + 1)) * 40;
                pl1p[base + lr]      = f2bf(fmaxf(m0r[it] + bia0, 0.0f));
                pl1p[base + 16 + lr] = f2bf(fmaxf(m1r[it] + bia1, 0.0f));
            }
        }
    }
    __syncthreads();

    // phase 3: conv2 MFMA, wave-per-oc-tile (B-frags once, 7 pyp unrolled)
    {
        bf16x8 bfr[9];
        #pragma unroll
        for (int s = 0; s < 9; ++s)
            bfr[s] = *(const bf16x8*)(W2gT + (wv * 16 + lr) * 296 + s * 32 + lg * 8);
        float bias2 = b2[wv * 16 + lr];

        #pragma unroll
        for (int pyp = 0; pyp < 7; ++pyp) {
            int py0 = pyp * 2;
            bf16x8 f[4][3];
            #pragma unroll
            for (int j = 0; j < 4; ++j)
                #pragma unroll
                for (int kx = 0; kx < 3; ++kx)
                    f[j][kx] = *(const bf16x8*)(pl1p + ((py0 + j) * 18 + (lr + kx)) * 40 + lg * 8);
            f32x4 acc0 = {bias2, bias2, bias2, bias2};
            f32x4 acc1 = acc0;
            #pragma unroll
            for (int ky = 0; ky < 3; ++ky)
                #pragma unroll
                for (int kx = 0; kx < 3; ++kx) {
                    acc0 = __builtin_amdgcn_mfma_f32_16x16x32_bf16(f[ky][kx],     bfr[ky * 3 + kx], acc0, 0, 0, 0);
                    acc1 = __builtin_amdgcn_mfma_f32_16x16x32_bf16(f[ky + 1][kx], bfr[ky * 3 + kx], acc1, 0, 0, 0);
                }
            float v0 = fmaxf(fmaxf(fmaxf(acc0[0], acc0[1]), fmaxf(acc1[0], acc1[1])), 0.0f);
            float v1 = fmaxf(fmaxf(fmaxf(acc0[2], acc0[3]), fmaxf(acc1[2], acc1[3])), 0.0f);
            int px0 = lg * 2, px1 = px0 + 1;
            size_t base = (size_t)i * 3136 + (size_t)(pyp * 7) * 64 + wv * 16 + lr;
            PL2[base + (size_t)px0 * 64] = f2bf(v0);
            if (px1 < 7) PL2[base + (size_t)px1 * 64] = f2bf(v1);
        }
    }
}

// 128x64-tile bf16 GEMM: C[M][N] = A[M][K]*BT[N][K]^T + bias. BK=64, 4 waves
// (2x2, per-wave 64x32 out), double-buffered swizzled LDS. Grid (M/128, N/64).
template<bool RELU, bool OUT_BF16>
__global__ __launch_bounds__(256) void gemm_bt128_kernel(
        const ushort* __restrict__ A, const ushort* __restrict__ BT,
        const float* __restrict__ bias, void* __restrict__ Cout,
        int M, int N, int K) {
    __shared__ __align__(16) ushort lds[2][12288];   // A: units 0..1023, B: units 1024..1535
    int t = threadIdx.x;
    int w = t >> 6, l = t & 63;
    int lr = l & 15, lc = l >> 4;
    int wm = w >> 1, wn = w & 1;
    int bm = blockIdx.x, bn = blockIdx.y;
    int NKt = K >> 6;

    const ushort* Ab = A + (size_t)bm * 128 * K;
    const ushort* Bb = BT + (size_t)bn * 64 * K;

    int rA[4], sA[4], dA[4];
    #pragma unroll
    for (int j = 0; j < 4; ++j) {
        int idx = t + 256 * j;
        rA[j] = idx >> 3; sA[j] = idx & 7;
        dA[j] = rA[j] * 8 + (sA[j] ^ (rA[j] & 7));
    }

    f32x4 acc[4][2] = {};

    uint4 tA[4], tB[2];
    #define GLOAD(kt) do { \
        tA[0] = *(const uint4*)(Ab + (size_t)rA[0] * K + (kt) * 64 + sA[0] * 8); \
        tA[1] = *(const uint4*)(Ab + (size_t)rA[1] * K + (kt) * 64 + sA[1] * 8); \
        tA[2] = *(const uint4*)(Ab + (size_t)rA[2] * K + (kt) * 64 + sA[2] * 8); \
        tA[3] = *(const uint4*)(Ab + (size_t)rA[3] * K + (kt) * 64 + sA[3] * 8); \
        tB[0] = *(const uint4*)(Bb + (size_t)rA[0] * K + (kt) * 64 + sA[0] * 8); \
        tB[1] = *(const uint4*)(Bb + (size_t)rA[1] * K + (kt) * 64 + sA[1] * 8); } while (0)
    #define LWRITE(bufi) do { \
        ((uint4*)lds[bufi])[dA[0]] = tA[0]; ((uint4*)lds[bufi])[dA[1]] = tA[1]; \
        ((uint4*)lds[bufi])[dA[2]] = tA[2]; ((uint4*)lds[bufi])[dA[3]] = tA[3]; \
        ((uint4*)lds[bufi])[1024 + dA[0]] = tB[0]; ((uint4*)lds[bufi])[1024 + dA[1]] = tB[1]; } while (0)

    GLOAD(0); LWRITE(0);
    int buf = 0;
    for (int kt = 0; kt < NKt; ++kt) {
        __syncthreads();
        if (kt + 1 < NKt) GLOAD(kt + 1);
        const ushort* Al = lds[buf];
        const ushort* Bl = lds[buf] + 8192;
        #pragma unroll
        for (int ks = 0; ks < 2; ++ks) {
            bf16x8 af[4], bg[2];
            #pragma unroll
            for (int mt = 0; mt < 4; ++mt) {
                int row = wm * 64 + mt * 16 + lr;
                int unit = row * 8 + ((ks * 4 + lc) ^ (row & 7));
                af[mt] = *(const bf16x8*)(Al + unit * 8);
            }
            #pragma unroll
            for (int nt = 0; nt < 2; ++nt) {
                int row = wn * 32 + nt * 16 + lr;
                int unit = row * 8 + ((ks * 4 + lc) ^ (row & 7));
                bg[nt] = *(const bf16x8*)(Bl + unit * 8);
            }
            #pragma unroll
            for (int mt = 0; mt < 4; ++mt)
                #pragma unroll
                for (int nt = 0; nt < 2; ++nt)
                    acc[mt][nt] = __builtin_amdgcn_mfma_f32_16x16x32_bf16(af[mt], bg[nt], acc[mt][nt], 0, 0, 0);
        }
        if (kt + 1 < NKt) LWRITE(buf ^ 1);
        buf ^= 1;
    }

    #pragma unroll
    for (int nt = 0; nt < 2; ++nt) {
        int gcol = bn * 64 + wn * 32 + nt * 16 + lr;
        float bv = bias[gcol];
        #pragma unroll
        for (int mt = 0; mt < 4; ++mt) {
            #pragma unroll
            for (int rg = 0; rg < 4; ++rg) {
                int grow = bm * 128 + wm * 64 + mt * 16 + lc * 4 + rg;
                float vv = acc[mt][nt][rg] + bv;
                if (RELU) vv = fmaxf(vv, 0.0f);
                if (OUT_BF16) ((ushort*)Cout)[(size_t)grow * N + gcol] = f2bf(vv);
                else          ((float*)Cout)[(size_t)grow * N + gcol] = vv;
            }
        }
    }
    #undef GLOAD
    #undef LWRITE
}

// 64x64-tile bf16 GEMM (R9-proven) — kept for proj2 (N=128)
template<bool RELU, bool OUT_BF16>
__global__ __launch_bounds__(256) void gemm_bt_kernel(
        const ushort* __restrict__ A, const ushort* __restrict__ BT,
        const float* __restrict__ bias, void* __restrict__ Cout,
        int M, int N, int K) {
    __shared__ __align__(16) ushort lds[2][2][4096];   // [buf][A/B][64*64] bf16
    int t = threadIdx.x;
    int w = t >> 6, l = t & 63;
    int lr = l & 15, lc = l >> 4;
    int wm = w >> 1, wn = w & 1;
    int bm = blockIdx.x, bn = blockIdx.y;
    int NKt = K >> 6;

    const ushort* Ab = A + (size_t)bm * 64 * K;
    const ushort* Bb = BT + (size_t)bn * 64 * K;

    int r0 = t >> 3, s0 = t & 7;
    int c1i = t + 256;
    int r1 = c1i >> 3, s1 = c1i & 7;
    int d0 = r0 * 8 + (s0 ^ (r0 & 7));
    int d1 = r1 * 8 + (s1 ^ (r1 & 7));

    f32x4 acc[2][2] = {};

    uint4 tA0, tA1, tB0, tB1;
    #define GLOAD(kt) do { \
        tA0 = *(const uint4*)(Ab + (size_t)r0 * K + (kt) * 64 + s0 * 8); \
        tA1 = *(const uint4*)(Ab + (size_t)r1 * K + (kt) * 64 + s1 * 8); \
        tB0 = *(const uint4*)(Bb + (size_t)r0 * K + (kt) * 64 + s0 * 8); \
        tB1 = *(const uint4*)(Bb + (size_t)r1 * K + (kt) * 64 + s1 * 8); } while (0)
    #define LWRITE(bufi) do { \
        ((uint4*)lds[bufi][0])[d0] = tA0; ((uint4*)lds[bufi][0])[d1] = tA1; \
        ((uint4*)lds[bufi][1])[d0] = tB0; ((uint4*)lds[bufi][1])[d1] = tB1; } while (0)

    GLOAD(0); LWRITE(0);
    int buf = 0;
    for (int kt = 0; kt < NKt; ++kt) {
        __syncthreads();
        if (kt + 1 < NKt) GLOAD(kt + 1);
        const ushort* Al = lds[buf][0];
        const ushort* Bl = lds[buf][1];
        #pragma unroll
        for (int ks = 0; ks < 2; ++ks) {
            bf16x8 af[2], bg[2];
            #pragma unroll
            for (int mt = 0; mt < 2; ++mt) {
                int row = wm * 32 + mt * 16 + lr;
                int unit = row * 8 + ((ks * 4 + lc) ^ (row & 7));
                af[mt] = *(const bf16x8*)(Al + unit * 8);
            }
            #pragma unroll
            for (int nt = 0; nt < 2; ++nt) {
                int row = wn * 32 + nt * 16 + lr;
                int unit = row * 8 + ((ks * 4 + lc) ^ (row & 7));
                bg[nt] = *(const bf16x8*)(Bl + unit * 8);
            }
            #pragma unroll
            for (int mt = 0; mt < 2; ++mt)
                #pragma unroll
                for (int nt = 0; nt < 2; ++nt)
                    acc[mt][nt] = __builtin_amdgcn_mfma_f32_16x16x32_bf16(af[mt], bg[nt], acc[mt][nt], 0, 0, 0);
        }
        if (kt + 1 < NKt) LWRITE(buf ^ 1);
        buf ^= 1;
    }

    #pragma unroll
    for (int nt = 0; nt < 2; ++nt) {
        int gcol = bn * 64 + wn * 32 + nt * 16 + lr;
        float bv = bias[gcol];
        #pragma unroll
        for (int mt = 0; mt < 2; ++mt) {
            #pragma unroll
            for (int rg = 0; rg < 4; ++rg) {
                int grow = bm * 64 + wm * 32 + mt * 16 + lc * 4 + rg;
                float vv = acc[mt][nt][rg] + bv;
                if (RELU) vv = fmaxf(vv, 0.0f);
                if (OUT_BF16) ((ushort*)Cout)[(size_t)grow * N + gcol] = f2bf(vv);
                else          ((float*)Cout)[(size_t)grow * N + gcol] = vv;
            }
        }
    }
    #undef GLOAD
    #undef LWRITE
}

// ---------------- launch ----------------
extern "C" void kernel_launch(void* const* d_in, const int* in_sizes, int n_in,
                              void* d_out, int out_size, void* d_ws, size_t ws_size,
                              hipStream_t stream) {
    const float* x   = (const float*)d_in[0];
    const float* W1  = (const float*)d_in[1];
    const float* b1  = (const float*)d_in[2];
    const float* W2  = (const float*)d_in[3];
    const float* b2  = (const float*)d_in[4];
    const float* Wf  = (const float*)d_in[5];
    const float* bf  = (const float*)d_in[6];
    const float* Wp1 = (const float*)d_in[7];
    const float* bp1 = (const float*)d_in[8];
    const float* Wp2 = (const float*)d_in[9];
    const float* bp2 = (const float*)d_in[10];

    float* ws     = (float*)d_ws;
    float* P      = ws + P_OFF;
    uint32_t* NK  = (uint32_t*)(ws + NK_OFF);
    ushort* W2gT  = (ushort*)(ws + W2GT_OFF);
    ushort* WfB   = (ushort*)(ws + WFB_OFF);
    ushort* Wp1B  = (ushort*)(ws + WP1B_OFF);
    ushort* Wp2B  = (ushort*)(ws + WP2B_OFF);
    float* AUG    = ws + AUG_OFF;
    ushort* PL2   = (ushort*)(ws + PL2_OFF);
    ushort* Hb    = (ushort*)(ws + H_OFF);
    ushort* P1    = (ushort*)(ws + AUG_OFF);   // alias: AUG dead before proj1 writes
    float* out    = (float*)d_out;

    param_kernel<<<32, 256, 0, stream>>>(P, NK);
    wprep_w2<<<74, 256, 0, stream>>>(W2, W2gT);
    wprep_wf<<<6272, 256, 0, stream>>>(Wf, WfB);
    wprep_cast<<<1024, 256, 0, stream>>>(Wp1, Wp1B, 512 * 512);
    wprep_cast<<<256, 256, 0, stream>>>(Wp2, Wp2B, 128 * 512);

    for (int v = 0; v < 2; ++v) {
        augment_kernel<<<4096, 256, 0, stream>>>(x, P, NK, AUG, v);
        conv12_kernel<<<4096, 256, 0, stream>>>(AUG, W1, b1, W2gT, b2, PL2);
        gemm_bt128_kernel<false, true><<<dim3(32, 8), 256, 0, stream>>>(
            PL2, WfB, bf, Hb, 4096, 512, 3136);
        gemm_bt128_kernel<true, true><<<dim3(32, 8), 256, 0, stream>>>(
            Hb, Wp1B, bp1, P1, 4096, 512, 512);
        gemm_bt_kernel<false, false><<<dim3(64, 2), 256, 0, stream>>>(
            P1, Wp2B, bp2, out + (size_t)v * 4096 * 128, 4096, 128, 512);
    }
}

// Round 14
// 266.565 us; speedup vs baseline: 1.5400x; 1.5400x over previous
//
#include <hip/hip_runtime.h>
#include <stdint.h>
#include <math.h>

typedef __attribute__((ext_vector_type(8))) short bf16x8;
typedef __attribute__((ext_vector_type(4))) float f32x4;

__device__ __forceinline__ ushort f2bf(float f) {      // RTNE, finite inputs
    uint32_t u = __float_as_uint(f);
    u += 0x7fffu + ((u >> 16) & 1u);
    return (ushort)(u >> 16);
}

// ---------------- Threefry-2x32 (JAX-exact, partitionable mode) ----------------
__device__ __forceinline__ uint32_t rotl32(uint32_t v, int r) {
    return (v << r) | (v >> (32 - r));
}

__device__ __forceinline__ void threefry(uint32_t k0, uint32_t k1,
                                         uint32_t c0, uint32_t c1,
                                         uint32_t& o0, uint32_t& o1) {
    uint32_t ks2 = k0 ^ k1 ^ 0x1BD11BDAu;
    uint32_t x0 = c0 + k0, x1 = c1 + k1;
    x0 += x1; x1 = rotl32(x1, 13); x1 ^= x0;
    x0 += x1; x1 = rotl32(x1, 15); x1 ^= x0;
    x0 += x1; x1 = rotl32(x1, 26); x1 ^= x0;
    x0 += x1; x1 = rotl32(x1,  6); x1 ^= x0;
    x0 += k1;  x1 += ks2 + 1u;
    x0 += x1; x1 = rotl32(x1, 17); x1 ^= x0;
    x0 += x1; x1 = rotl32(x1, 29); x1 ^= x0;
    x0 += x1; x1 = rotl32(x1, 16); x1 ^= x0;
    x0 += x1; x1 = rotl32(x1, 24); x1 ^= x0;
    x0 += ks2; x1 += k0 + 2u;
    x0 += x1; x1 = rotl32(x1, 13); x1 ^= x0;
    x0 += x1; x1 = rotl32(x1, 15); x1 ^= x0;
    x0 += x1; x1 = rotl32(x1, 26); x1 ^= x0;
    x0 += x1; x1 = rotl32(x1,  6); x1 ^= x0;
    x0 += k0;  x1 += k1 + 3u;
    x0 += x1; x1 = rotl32(x1, 17); x1 ^= x0;
    x0 += x1; x1 = rotl32(x1, 29); x1 ^= x0;
    x0 += x1; x1 = rotl32(x1, 16); x1 ^= x0;
    x0 += x1; x1 = rotl32(x1, 24); x1 ^= x0;
    x0 += k1;  x1 += ks2 + 4u;
    x0 += x1; x1 = rotl32(x1, 13); x1 ^= x0;
    x0 += x1; x1 = rotl32(x1, 15); x1 ^= x0;
    x0 += x1; x1 = rotl32(x1, 26); x1 ^= x0;
    x0 += x1; x1 = rotl32(x1,  6); x1 ^= x0;
    x0 += ks2; x1 += k0 + 5u;
    o0 = x0; o1 = x1;
}

__device__ __forceinline__ uint32_t rbits32(uint32_t k0, uint32_t k1, uint32_t idx) {
    uint32_t o0, o1;
    threefry(k0, k1, 0u, idx, o0, o1);
    return o0 ^ o1;
}

__device__ __forceinline__ float u01_from_bits(uint32_t bits) {
    return __uint_as_float((bits >> 9) | 0x3f800000u) - 1.0f;
}

__device__ float erfinv_xla(float x) {
    #pragma clang fp contract(off)
    float w = -log1pf(-x * x);
    float p;
    if (w < 5.0f) {
        w = w - 2.5f;
        p = 2.81022636e-08f;
        p = 3.43273939e-07f + p * w;
        p = -3.5233877e-06f + p * w;
        p = -4.39150654e-06f + p * w;
        p = 0.00021858087f + p * w;
        p = -0.00125372503f + p * w;
        p = -0.00417768164f + p * w;
        p = 0.246640727f + p * w;
        p = 1.50140941f + p * w;
    } else {
        w = sqrtf(w) - 3.0f;
        p = -0.000200214257f;
        p = 0.000100950558f + p * w;
        p = 0.00134934322f + p * w;
        p = -0.00367342844f + p * w;
        p = 0.00573950773f + p * w;
        p = -0.0076224613f + p * w;
        p = 0.00943887047f + p * w;
        p = 1.00167406f + p * w;
        p = 2.83297682f + p * w;
    }
    return p * x;
}

// ---------------- workspace layout (float offsets) ----------------
#define P_OFF      0           // 8192*12
#define NK_OFF     98304       // 4 u32 (16 f reserved)
#define W2GT_OFF   98320       // 64*296 bf16 = 9472 f
#define WFB_OFF    107792      // 512*3136 bf16 = 802816 f
#define WP1B_OFF   910608      // 512*512 bf16 = 131072 f
#define WP2B_OFF   1041680     // 128*512 bf16 = 32768 f
#define AUG_OFF    1074448     // 4096*784 f32 (P1 bf16 aliases this region)
#define PL2_OFF    4285712     // 4096*3136 bf16 = 6422528 f
#define H_OFF      10708240    // 4096*512 bf16 = 1048576 f
// end = 11,756,816 floats = 47.0 MB

// ---------------- kernels ----------------
__global__ void param_kernel(float* __restrict__ P, uint32_t* __restrict__ NK) {
    #pragma clang fp contract(off)
    int gid = blockIdx.x * blockDim.x + threadIdx.x;
    if (gid >= 8192) return;
    int v = gid >> 12;
    int i = gid & 4095;

    uint32_t kv0, kv1;
    threefry(0u, 42u, 0u, (uint32_t)v, kv0, kv1);

    uint32_t sk0[11], sk1[11];
    #pragma unroll
    for (int j = 0; j < 11; ++j) threefry(kv0, kv1, 0u, (uint32_t)j, sk0[j], sk1[j]);

    float u[10];
    #pragma unroll
    for (int j = 0; j < 10; ++j) u[j] = u01_from_bits(rbits32(sk0[j], sk1[j], (uint32_t)i));

    float crop = floorf(28.0f * (0.7f + 0.3f * u[0]));
    float top  = floorf((28.0f - crop) * u[1]);
    float left = floorf((28.0f - crop) * u[2]);
    float flip = (u[3] < 0.5f) ? 1.0f : 0.0f;
    float rot  = (u[4] < 0.8f) ? 1.0f : 0.0f;
    float rad  = ((20.0f * u[5] - 10.0f) * 3.14159274101257324f) / 180.0f;
    float cj   = (u[6] < 0.8f) ? 1.0f : 0.0f;
    float bb   = 0.2f * u[7] - 0.1f;
    float cc   = 0.8f + 0.4f * u[8];
    float na   = (u[9] < 0.5f) ? 1.0f : 0.0f;

    float* p = P + gid * 12;
    p[0] = crop; p[1] = top; p[2] = left; p[3] = flip; p[4] = rot;
    p[5] = rad;  p[6] = cj;  p[7] = bb;   p[8] = cc;   p[9] = na;
    p[10] = cosf(rad); p[11] = sinf(rad);   // hoisted (identical bits to in-kernel cosf/sinf)

    if (i == 0) { NK[v * 2] = sk0[10]; NK[v * 2 + 1] = sk1[10]; }
}

// W2 (64,32,3,3) -> W2gT[oc][k=(ky*3+kx)*32+ic], padded row stride 296, bf16
__global__ void wprep_w2(const float* __restrict__ W2, ushort* __restrict__ W2gT) {
    int idx = blockIdx.x * 256 + threadIdx.x;
    if (idx >= 64 * 296) return;
    int oc = idx / 296, k = idx % 296;
    float v = 0.0f;
    if (k < 288) {
        int s = k >> 5, ic = k & 31;
        int ky = s / 3, kx = s % 3;
        v = W2[((oc * 32 + ic) * 3 + ky) * 3 + kx];
    }
    W2gT[idx] = f2bf(v);
}

// Wf (512, 3136=oc*49+pos) -> WfB[n][k'=pos*64+oc] bf16
__global__ void wprep_wf(const float* __restrict__ Wf, ushort* __restrict__ WfB) {
    int idx = blockIdx.x * 256 + threadIdx.x;
    if (idx >= 512 * 3136) return;
    int n = idx / 3136, kp = idx % 3136;
    int pos = kp >> 6, oc = kp & 63;
    WfB[idx] = f2bf(Wf[n * 3136 + oc * 49 + pos]);
}

__global__ void wprep_cast(const float* __restrict__ src, ushort* __restrict__ dst, int n) {
    int idx = blockIdx.x * 256 + threadIdx.x;
    if (idx < n) dst[idx] = f2bf(src[idx]);
}

// Block-per-image augment (R12-proven: coord table + hoisted trig)
__global__ __launch_bounds__(256) void augment_kernel(const float* __restrict__ x,
                                                      const float* __restrict__ P,
                                                      const uint32_t* __restrict__ NK,
                                                      float* __restrict__ AUG, int v) {
    #pragma clang fp contract(off)
    int i = blockIdx.x;                 // 0..4095
    int r = v * 4096 + i;
    int t = threadIdx.x;
    __shared__ float img[784];
    __shared__ float s1[784];
    __shared__ float srctab[28];

    const float* p = P + r * 12;
    float crop = p[0], top = p[1], left = p[2];
    int flip = (p[3] != 0.0f);
    int rot  = (p[4] != 0.0f);
    int cj = (p[6] != 0.0f);
    float bb = p[7], cc = p[8];
    int na = (p[9] != 0.0f);
    float cs = p[10], sn = p[11];
    uint32_t nk0 = NK[v * 2], nk1 = NK[v * 2 + 1];

    for (int q = t; q < 784; q += 256) img[q] = x[i * 784 + q];
    if (t < 28) {
        float j = (float)t + 0.5f;
        float s = j * crop / 28.0f - 0.5f;
        srctab[t] = fminf(fmaxf(s, 0.0f), crop - 1.0f);
    }
    __syncthreads();

    for (int q = t; q < 784; q += 256) {
        int py = q / 28, px = q - (q / 28) * 28;
        int sxcol = flip ? (27 - px) : px;
        float yy = srctab[py] + top;
        float xx = srctab[sxcol] + left;
        float y0f = floorf(yy), x0f = floorf(xx);
        float wy = yy - y0f, wx = xx - x0f;
        int y0 = (int)y0f, x0 = (int)x0f;

        int yc0 = min(max(y0, 0), 27),     xc0 = min(max(x0, 0), 27);
        int yc1 = min(max(y0 + 1, 0), 27), xc1 = min(max(x0 + 1, 0), 27);
        float g00 = img[yc0 * 28 + xc0];
        float g01 = img[yc0 * 28 + xc1];
        float g10 = img[yc1 * 28 + xc0];
        float g11 = img[yc1 * 28 + xc1];
        float val = g00 * (1.0f - wy) * (1.0f - wx) + g01 * (1.0f - wy) * wx
                  + g10 * wy * (1.0f - wx) + g11 * wy * wx;
        s1[q] = val;
    }
    __syncthreads();

    for (int q = t; q < 784; q += 256) {
        int py = q / 28, px = q - (q / 28) * 28;
        float val;
        if (rot) {
            float Yn = (2.0f * (float)py + 1.0f) / 28.0f - 1.0f;
            float Xn = (2.0f * (float)px + 1.0f) / 28.0f - 1.0f;
            float xs = cs * Xn - sn * Yn;
            float ys = sn * Xn + cs * Yn;
            float ix = ((xs + 1.0f) * 28.0f - 1.0f) / 2.0f;
            float iy = ((ys + 1.0f) * 28.0f - 1.0f) / 2.0f;
            float y0f = floorf(iy), x0f = floorf(ix);
            float wy = iy - y0f, wx = ix - x0f;
            int y0 = (int)y0f, x0 = (int)x0f;
            float g[2][2];
            #pragma unroll
            for (int dy = 0; dy < 2; ++dy) {
                #pragma unroll
                for (int dx = 0; dx < 2; ++dx) {
                    int yi = y0 + dy, xi = x0 + dx;
                    int yc = min(max(yi, 0), 27), xc = min(max(xi, 0), 27);
                    float vv = s1[yc * 28 + xc];
                    float valid = (yi >= 0 && yi < 28 && xi >= 0 && xi < 28) ? 1.0f : 0.0f;
                    g[dy][dx] = vv * valid;
                }
            }
            val = g[0][0] * (1.0f - wy) * (1.0f - wx) + g[0][1] * (1.0f - wy) * wx
                + g[1][0] * wy * (1.0f - wx) + g[1][1] * wy * wx;
        } else {
            val = s1[q];
        }

        if (cj) {
            float vc = fminf(fmaxf(val + bb, 0.0f), 1.0f);
            val = fminf(fmaxf((vc - 0.5f) * cc + 0.5f, 0.0f), 1.0f);
        }

        if (na) {
            int idx = i * 784 + q;
            uint32_t bits = rbits32(nk0, nk1, (uint32_t)idx);
            float f = u01_from_bits(bits);
            const float lo = -0.99999994f;
            float uu = f * 2.0f + lo;
            uu = fmaxf(lo, uu);
            float n = 1.4142135623730951f * erfinv_xla(uu);
            val = fminf(fmaxf(val + 0.05f * n, 0.0f), 1.0f);
        }

        AUG[i * 784 + q] = (val - 0.5f) / 0.5f;
    }
}

// conv12 (R12-proven): conv1 MFMA (thread-per-pooled-position im2col) + conv2
// MFMA (wave-per-oc-tile). A1/pl1p alias one LDS buffer.
__global__ __launch_bounds__(256) void conv12_kernel(
        const float* __restrict__ AUG,
        const float* __restrict__ W1, const float* __restrict__ b1,
        const ushort* __restrict__ W2gT, const float* __restrict__ b2,
        ushort* __restrict__ PL2) {
    int i = blockIdx.x, t = threadIdx.x;
    __shared__ __align__(16) ushort buf[12576];           // 25152 B: A1, then pl1p
    __shared__ __align__(16) ushort w1sT[32 * 32];        // 2048 B  [oc][k]
    ushort* A1   = buf;
    ushort* pl1p = buf;

    {
        int q0 = t * 4;
        #pragma unroll
        for (int j = 0; j < 4; ++j) {
            int q = q0 + j;
            int oc = q >> 5, k = q & 31;
            w1sT[q] = (k < 9) ? f2bf(W1[oc * 9 + k]) : (ushort)0;
        }
    }

    const float* Ai = AUG + (size_t)i * 784;
    if (t < 196) {
        int py = t / 14, px = t - (t / 14) * 14;
        int ybase = 2 * py - 1, xbase = 2 * px - 1;
        uint32_t u[4][4];
        #pragma unroll
        for (int ry = 0; ry < 4; ++ry) {
            int yy = ybase + ry;
            bool yok = (unsigned)yy < 28u;
            const float* rowp = Ai + yy * 28;
            #pragma unroll
            for (int rx = 0; rx < 4; ++rx) {
                int xx = xbase + rx;
                float vv = (yok && (unsigned)xx < 28u) ? rowp[xx] : 0.0f;
                u[ry][rx] = (uint32_t)f2bf(vv);
            }
        }
        #pragma unroll
        for (int w = 0; w < 4; ++w) {
            int dy = w >> 1, dx = w & 1;
            uint4 W0, W1v;
            W0.x = u[dy][dx]     | (u[dy][dx + 1] << 16);
            W0.y = u[dy][dx + 2] | (u[dy + 1][dx] << 16);
            W0.z = u[dy + 1][dx + 1] | (u[dy + 1][dx + 2] << 16);
            W0.w = u[dy + 2][dx]     | (u[dy + 2][dx + 1] << 16);
            W1v.x = u[dy + 2][dx + 2];
            W1v.y = 0; W1v.z = 0; W1v.w = 0;
            ((uint4*)A1)[(t * 4 + w) * 2]     = W0;
            ((uint4*)A1)[(t * 4 + w) * 2 + 1] = W1v;
        }
    }
    __syncthreads();

    int l = t & 63, wv = t >> 6;
    int lr = l & 15, lg = l >> 4;

    float m0r[13], m1r[13];
    {
        bf16x8 bA = *(const bf16x8*)(w1sT + lr * 32 + lg * 8);
        bf16x8 bB = *(const bf16x8*)(w1sT + (16 + lr) * 32 + lg * 8);
        #pragma unroll
        for (int it = 0; it < 13; ++it) {
            int tt = wv + it * 4;
            if (tt < 49) {
                bf16x8 af = *(const bf16x8*)(A1 + (tt * 16 + lr) * 16 + lg * 8);
                f32x4 a0 = {0.0f, 0.0f, 0.0f, 0.0f};
                f32x4 a1acc = {0.0f, 0.0f, 0.0f, 0.0f};
                a0    = __builtin_amdgcn_mfma_f32_16x16x32_bf16(af, bA, a0, 0, 0, 0);
                a1acc = __builtin_amdgcn_mfma_f32_16x16x32_bf16(af, bB, a1acc, 0, 0, 0);
                m0r[it] = fmaxf(fmaxf(a0[0], a0[1]), fmaxf(a0[2], a0[3]));
                m1r[it] = fmaxf(fmaxf(a1acc[0], a1acc[1]), fmaxf(a1acc[2], a1acc[3]));
            }
        }
    }
    __syncthreads();

    for (int q = t; q < 1440; q += 256) ((uint4*)pl1p)[q] = uint4{0, 0, 0, 0};
    __syncthreads();

    {
        float bia0 = b1[lr], bia1 = b1[16 + lr];
        #pragma unroll
        for (int it = 0; it < 13; ++it) {
            int tt = wv + it * 4;
            if (tt < 49) {
                int pidx = tt * 4 + lg;
                int py = pidx / 14, px = pidx - py * 14;
                int base = ((py + 1) * 18 + (px + 1)) * 40;
                pl1p[base + lr]      = f2bf(fmaxf(m0r[it] + bia0, 0.0f));
                pl1p[base + 16 + lr] = f2bf(fmaxf(m1r[it] + bia1, 0.0f));
            }
        }
    }
    __syncthreads();

    {
        bf16x8 bfr[9];
        #pragma unroll
        for (int s = 0; s < 9; ++s)
            bfr[s] = *(const bf16x8*)(W2gT + (wv * 16 + lr) * 296 + s * 32 + lg * 8);
        float bias2 = b2[wv * 16 + lr];

        #pragma unroll
        for (int pyp = 0; pyp < 7; ++pyp) {
            int py0 = pyp * 2;
            bf16x8 f[4][3];
            #pragma unroll
            for (int j = 0; j < 4; ++j)
                #pragma unroll
                for (int kx = 0; kx < 3; ++kx)
                    f[j][kx] = *(const bf16x8*)(pl1p + ((py0 + j) * 18 + (lr + kx)) * 40 + lg * 8);
            f32x4 acc0 = {bias2, bias2, bias2, bias2};
            f32x4 acc1 = acc0;
            #pragma unroll
            for (int ky = 0; ky < 3; ++ky)
                #pragma unroll
                for (int kx = 0; kx < 3; ++kx) {
                    acc0 = __builtin_amdgcn_mfma_f32_16x16x32_bf16(f[ky][kx],     bfr[ky * 3 + kx], acc0, 0, 0, 0);
                    acc1 = __builtin_amdgcn_mfma_f32_16x16x32_bf16(f[ky + 1][kx], bfr[ky * 3 + kx], acc1, 0, 0, 0);
                }
            float v0 = fmaxf(fmaxf(fmaxf(acc0[0], acc0[1]), fmaxf(acc1[0], acc1[1])), 0.0f);
            float v1 = fmaxf(fmaxf(fmaxf(acc0[2], acc0[3]), fmaxf(acc1[2], acc1[3])), 0.0f);
            int px0 = lg * 2, px1 = px0 + 1;
            size_t base = (size_t)i * 3136 + (size_t)(pyp * 7) * 64 + wv * 16 + lr;
            PL2[base + (size_t)px0 * 64] = f2bf(v0);
            if (px1 < 7) PL2[base + (size_t)px1 * 64] = f2bf(v1);
        }
    }
}

// 64x64-tile bf16 GEMM, 8 WAVES (512 thr): same tile/LDS/traffic as the proven
// 4-wave version but 2x the waves/CU for latency hiding. Wave grid 2x4
// (per-wave 32x16 out, acc[2][1]). K-order per output element identical ->
// bit-identical results.
template<bool RELU, bool OUT_BF16>
__global__ __launch_bounds__(512) void gemm_bt8w_kernel(
        const ushort* __restrict__ A, const ushort* __restrict__ BT,
        const float* __restrict__ bias, void* __restrict__ Cout,
        int M, int N, int K) {
    __shared__ __align__(16) ushort lds[2][2][4096];   // [buf][A/B][64*64] bf16
    int t = threadIdx.x;                // 0..511
    int w = t >> 6, l = t & 63;
    int lr = l & 15, lc = l >> 4;
    int wm = w >> 2, wn = w & 3;        // 2 x 4 wave grid
    int bm = blockIdx.x, bn = blockIdx.y;
    int NKt = K >> 6;

    const ushort* Ab = A + (size_t)bm * 64 * K;
    const ushort* Bb = BT + (size_t)bn * 64 * K;

    int r0 = t >> 3, s0 = t & 7;        // 512 threads cover 512 uint4 units
    int d0 = r0 * 8 + (s0 ^ (r0 & 7));

    f32x4 acc[2] = {};                  // acc[mt], single n-frag per wave

    uint4 tA0, tB0;
    #define GLOAD(kt) do { \
        tA0 = *(const uint4*)(Ab + (size_t)r0 * K + (kt) * 64 + s0 * 8); \
        tB0 = *(const uint4*)(Bb + (size_t)r0 * K + (kt) * 64 + s0 * 8); } while (0)
    #define LWRITE(bufi) do { \
        ((uint4*)lds[bufi][0])[d0] = tA0; \
        ((uint4*)lds[bufi][1])[d0] = tB0; } while (0)

    GLOAD(0); LWRITE(0);
    int buf = 0;
    for (int kt = 0; kt < NKt; ++kt) {
        __syncthreads();
        if (kt + 1 < NKt) GLOAD(kt + 1);
        const ushort* Al = lds[buf][0];
        const ushort* Bl = lds[buf][1];
        #pragma unroll
        for (int ks = 0; ks < 2; ++ks) {
            bf16x8 af[2], bg;
            #pragma unroll
            for (int mt = 0; mt < 2; ++mt) {
                int row = wm * 32 + mt * 16 + lr;
                int unit = row * 8 + ((ks * 4 + lc) ^ (row & 7));
                af[mt] = *(const bf16x8*)(Al + unit * 8);
            }
            {
                int row = wn * 16 + lr;
                int unit = row * 8 + ((ks * 4 + lc) ^ (row & 7));
                bg = *(const bf16x8*)(Bl + unit * 8);
            }
            #pragma unroll
            for (int mt = 0; mt < 2; ++mt)
                acc[mt] = __builtin_amdgcn_mfma_f32_16x16x32_bf16(af[mt], bg, acc[mt], 0, 0, 0);
        }
        if (kt + 1 < NKt) LWRITE(buf ^ 1);
        buf ^= 1;
    }
    #undef GLOAD
    #undef LWRITE

    int gcol = bn * 64 + wn * 16 + lr;
    float bv = bias[gcol];
    #pragma unroll
    for (int mt = 0; mt < 2; ++mt) {
        #pragma unroll
        for (int rg = 0; rg < 4; ++rg) {
            int grow = bm * 64 + wm * 32 + mt * 16 + lc * 4 + rg;
            float vv = acc[mt][rg] + bv;
            if (RELU) vv = fmaxf(vv, 0.0f);
            if (OUT_BF16) ((ushort*)Cout)[(size_t)grow * N + gcol] = f2bf(vv);
            else          ((float*)Cout)[(size_t)grow * N + gcol] = vv;
        }
    }
}

// ---------------- launch ----------------
extern "C" void kernel_launch(void* const* d_in, const int* in_sizes, int n_in,
                              void* d_out, int out_size, void* d_ws, size_t ws_size,
                              hipStream_t stream) {
    const float* x   = (const float*)d_in[0];
    const float* W1  = (const float*)d_in[1];
    const float* b1  = (const float*)d_in[2];
    const float* W2  = (const float*)d_in[3];
    const float* b2  = (const float*)d_in[4];
    const float* Wf  = (const float*)d_in[5];
    const float* bf  = (const float*)d_in[6];
    const float* Wp1 = (const float*)d_in[7];
    const float* bp1 = (const float*)d_in[8];
    const float* Wp2 = (const float*)d_in[9];
    const float* bp2 = (const float*)d_in[10];

    float* ws     = (float*)d_ws;
    float* P      = ws + P_OFF;
    uint32_t* NK  = (uint32_t*)(ws + NK_OFF);
    ushort* W2gT  = (ushort*)(ws + W2GT_OFF);
    ushort* WfB   = (ushort*)(ws + WFB_OFF);
    ushort* Wp1B  = (ushort*)(ws + WP1B_OFF);
    ushort* Wp2B  = (ushort*)(ws + WP2B_OFF);
    float* AUG    = ws + AUG_OFF;
    ushort* PL2   = (ushort*)(ws + PL2_OFF);
    ushort* Hb    = (ushort*)(ws + H_OFF);
    ushort* P1    = (ushort*)(ws + AUG_OFF);   // alias: AUG dead before proj1 writes
    float* out    = (float*)d_out;

    param_kernel<<<32, 256, 0, stream>>>(P, NK);
    wprep_w2<<<74, 256, 0, stream>>>(W2, W2gT);
    wprep_wf<<<6272, 256, 0, stream>>>(Wf, WfB);
    wprep_cast<<<1024, 256, 0, stream>>>(Wp1, Wp1B, 512 * 512);
    wprep_cast<<<256, 256, 0, stream>>>(Wp2, Wp2B, 128 * 512);

    for (int v = 0; v < 2; ++v) {
        augment_kernel<<<4096, 256, 0, stream>>>(x, P, NK, AUG, v);
        conv12_kernel<<<4096, 256, 0, stream>>>(AUG, W1, b1, W2gT, b2, PL2);
        gemm_bt8w_kernel<false, true><<<dim3(64, 8), 512, 0, stream>>>(
            PL2, WfB, bf, Hb, 4096, 512, 3136);
        gemm_bt8w_kernel<true, true><<<dim3(64, 8), 512, 0, stream>>>(
            Hb, Wp1B, bp1, P1, 4096, 512, 512);
        gemm_bt8w_kernel<false, false><<<dim3(64, 2), 512, 0, stream>>>(
            P1, Wp2B, bp2, out + (size_t)v * 4096 * 128, 4096, 128, 512);
    }
}

// Round 15
// 256.996 us; speedup vs baseline: 1.5974x; 1.0372x over previous
//
#include <hip/hip_runtime.h>
#include <stdint.h>
#include <math.h>

typedef __attribute__((ext_vector_type(8))) short bf16x8;
typedef __attribute__((ext_vector_type(4))) float f32x4;

__device__ __forceinline__ ushort f2bf(float f) {      // RTNE, finite inputs
    uint32_t u = __float_as_uint(f);
    u += 0x7fffu + ((u >> 16) & 1u);
    return (ushort)(u >> 16);
}

// ---------------- Threefry-2x32 (JAX-exact, partitionable mode) ----------------
__device__ __forceinline__ uint32_t rotl32(uint32_t v, int r) {
    return (v << r) | (v >> (32 - r));
}

__device__ __forceinline__ void threefry(uint32_t k0, uint32_t k1,
                                         uint32_t c0, uint32_t c1,
                                         uint32_t& o0, uint32_t& o1) {
    uint32_t ks2 = k0 ^ k1 ^ 0x1BD11BDAu;
    uint32_t x0 = c0 + k0, x1 = c1 + k1;
    x0 += x1; x1 = rotl32(x1, 13); x1 ^= x0;
    x0 += x1; x1 = rotl32(x1, 15); x1 ^= x0;
    x0 += x1; x1 = rotl32(x1, 26); x1 ^= x0;
    x0 += x1; x1 = rotl32(x1,  6); x1 ^= x0;
    x0 += k1;  x1 += ks2 + 1u;
    x0 += x1; x1 = rotl32(x1, 17); x1 ^= x0;
    x0 += x1; x1 = rotl32(x1, 29); x1 ^= x0;
    x0 += x1; x1 = rotl32(x1, 16); x1 ^= x0;
    x0 += x1; x1 = rotl32(x1, 24); x1 ^= x0;
    x0 += ks2; x1 += k0 + 2u;
    x0 += x1; x1 = rotl32(x1, 13); x1 ^= x0;
    x0 += x1; x1 = rotl32(x1, 15); x1 ^= x0;
    x0 += x1; x1 = rotl32(x1, 26); x1 ^= x0;
    x0 += x1; x1 = rotl32(x1,  6); x1 ^= x0;
    x0 += k0;  x1 += k1 + 3u;
    x0 += x1; x1 = rotl32(x1, 17); x1 ^= x0;
    x0 += x1; x1 = rotl32(x1, 29); x1 ^= x0;
    x0 += x1; x1 = rotl32(x1, 16); x1 ^= x0;
    x0 += x1; x1 = rotl32(x1, 24); x1 ^= x0;
    x0 += k1;  x1 += ks2 + 4u;
    x0 += x1; x1 = rotl32(x1, 13); x1 ^= x0;
    x0 += x1; x1 = rotl32(x1, 15); x1 ^= x0;
    x0 += x1; x1 = rotl32(x1, 26); x1 ^= x0;
    x0 += x1; x1 = rotl32(x1,  6); x1 ^= x0;
    x0 += ks2; x1 += k0 + 5u;
    o0 = x0; o1 = x1;
}

__device__ __forceinline__ uint32_t rbits32(uint32_t k0, uint32_t k1, uint32_t idx) {
    uint32_t o0, o1;
    threefry(k0, k1, 0u, idx, o0, o1);
    return o0 ^ o1;
}

__device__ __forceinline__ float u01_from_bits(uint32_t bits) {
    return __uint_as_float((bits >> 9) | 0x3f800000u) - 1.0f;
}

__device__ float erfinv_xla(float x) {
    #pragma clang fp contract(off)
    float w = -log1pf(-x * x);
    float p;
    if (w < 5.0f) {
        w = w - 2.5f;
        p = 2.81022636e-08f;
        p = 3.43273939e-07f + p * w;
        p = -3.5233877e-06f + p * w;
        p = -4.39150654e-06f + p * w;
        p = 0.00021858087f + p * w;
        p = -0.00125372503f + p * w;
        p = -0.00417768164f + p * w;
        p = 0.246640727f + p * w;
        p = 1.50140941f + p * w;
    } else {
        w = sqrtf(w) - 3.0f;
        p = -0.000200214257f;
        p = 0.000100950558f + p * w;
        p = 0.00134934322f + p * w;
        p = -0.00367342844f + p * w;
        p = 0.00573950773f + p * w;
        p = -0.0076224613f + p * w;
        p = 0.00943887047f + p * w;
        p = 1.00167406f + p * w;
        p = 2.83297682f + p * w;
    }
    return p * x;
}

// ---------------- workspace layout (float offsets) ----------------
#define P_OFF      0           // 8192*12
#define NK_OFF     98304       // 4 u32 (16 f reserved)
#define W2GT_OFF   98320       // 64*296 bf16 = 9472 f
#define WFB_OFF    107792      // 512*3136 bf16 = 802816 f
#define WP1B_OFF   910608      // 512*512 bf16 = 131072 f
#define WP2B_OFF   1041680     // 128*512 bf16 = 32768 f
#define AUG_OFF    1074448     // 4096*784 f32 (P1 bf16 aliases this region)
#define PL2_OFF    4285712     // 4096*3136 bf16 = 6422528 f
#define H_OFF      10708240    // 4096*512 bf16 = 1048576 f
// end = 11,756,816 floats = 47.0 MB

// ---------------- kernels ----------------
__global__ void param_kernel(float* __restrict__ P, uint32_t* __restrict__ NK) {
    #pragma clang fp contract(off)
    int gid = blockIdx.x * blockDim.x + threadIdx.x;
    if (gid >= 8192) return;
    int v = gid >> 12;
    int i = gid & 4095;

    uint32_t kv0, kv1;
    threefry(0u, 42u, 0u, (uint32_t)v, kv0, kv1);

    uint32_t sk0[11], sk1[11];
    #pragma unroll
    for (int j = 0; j < 11; ++j) threefry(kv0, kv1, 0u, (uint32_t)j, sk0[j], sk1[j]);

    float u[10];
    #pragma unroll
    for (int j = 0; j < 10; ++j) u[j] = u01_from_bits(rbits32(sk0[j], sk1[j], (uint32_t)i));

    float crop = floorf(28.0f * (0.7f + 0.3f * u[0]));
    float top  = floorf((28.0f - crop) * u[1]);
    float left = floorf((28.0f - crop) * u[2]);
    float flip = (u[3] < 0.5f) ? 1.0f : 0.0f;
    float rot  = (u[4] < 0.8f) ? 1.0f : 0.0f;
    float rad  = ((20.0f * u[5] - 10.0f) * 3.14159274101257324f) / 180.0f;
    float cj   = (u[6] < 0.8f) ? 1.0f : 0.0f;
    float bb   = 0.2f * u[7] - 0.1f;
    float cc   = 0.8f + 0.4f * u[8];
    float na   = (u[9] < 0.5f) ? 1.0f : 0.0f;

    float* p = P + gid * 12;
    p[0] = crop; p[1] = top; p[2] = left; p[3] = flip; p[4] = rot;
    p[5] = rad;  p[6] = cj;  p[7] = bb;   p[8] = cc;   p[9] = na;
    p[10] = cosf(rad); p[11] = sinf(rad);   // hoisted (identical bits to in-kernel cosf/sinf)

    if (i == 0) { NK[v * 2] = sk0[10]; NK[v * 2 + 1] = sk1[10]; }
}

// W2 (64,32,3,3) -> W2gT[oc][k=(ky*3+kx)*32+ic], padded row stride 296, bf16
__global__ void wprep_w2(const float* __restrict__ W2, ushort* __restrict__ W2gT) {
    int idx = blockIdx.x * 256 + threadIdx.x;
    if (idx >= 64 * 296) return;
    int oc = idx / 296, k = idx % 296;
    float v = 0.0f;
    if (k < 288) {
        int s = k >> 5, ic = k & 31;
        int ky = s / 3, kx = s % 3;
        v = W2[((oc * 32 + ic) * 3 + ky) * 3 + kx];
    }
    W2gT[idx] = f2bf(v);
}

// Wf (512, 3136=oc*49+pos) -> WfB[n][k'=pos*64+oc] bf16
__global__ void wprep_wf(const float* __restrict__ Wf, ushort* __restrict__ WfB) {
    int idx = blockIdx.x * 256 + threadIdx.x;
    if (idx >= 512 * 3136) return;
    int n = idx / 3136, kp = idx % 3136;
    int pos = kp >> 6, oc = kp & 63;
    WfB[idx] = f2bf(Wf[n * 3136 + oc * 49 + pos]);
}

__global__ void wprep_cast(const float* __restrict__ src, ushort* __restrict__ dst, int n) {
    int idx = blockIdx.x * 256 + threadIdx.x;
    if (idx < n) dst[idx] = f2bf(src[idx]);
}

// Block-per-image augment (R12-proven: coord table + hoisted trig)
__global__ __launch_bounds__(256) void augment_kernel(const float* __restrict__ x,
                                                      const float* __restrict__ P,
                                                      const uint32_t* __restrict__ NK,
                                                      float* __restrict__ AUG, int v) {
    #pragma clang fp contract(off)
    int i = blockIdx.x;                 // 0..4095
    int r = v * 4096 + i;
    int t = threadIdx.x;
    __shared__ float img[784];
    __shared__ float s1[784];
    __shared__ float srctab[28];

    const float* p = P + r * 12;
    float crop = p[0], top = p[1], left = p[2];
    int flip = (p[3] != 0.0f);
    int rot  = (p[4] != 0.0f);
    int cj = (p[6] != 0.0f);
    float bb = p[7], cc = p[8];
    int na = (p[9] != 0.0f);
    float cs = p[10], sn = p[11];
    uint32_t nk0 = NK[v * 2], nk1 = NK[v * 2 + 1];

    for (int q = t; q < 784; q += 256) img[q] = x[i * 784 + q];
    if (t < 28) {
        float j = (float)t + 0.5f;
        float s = j * crop / 28.0f - 0.5f;
        srctab[t] = fminf(fmaxf(s, 0.0f), crop - 1.0f);
    }
    __syncthreads();

    for (int q = t; q < 784; q += 256) {
        int py = q / 28, px = q - (q / 28) * 28;
        int sxcol = flip ? (27 - px) : px;
        float yy = srctab[py] + top;
        float xx = srctab[sxcol] + left;
        float y0f = floorf(yy), x0f = floorf(xx);
        float wy = yy - y0f, wx = xx - x0f;
        int y0 = (int)y0f, x0 = (int)x0f;

        int yc0 = min(max(y0, 0), 27),     xc0 = min(max(x0, 0), 27);
        int yc1 = min(max(y0 + 1, 0), 27), xc1 = min(max(x0 + 1, 0), 27);
        float g00 = img[yc0 * 28 + xc0];
        float g01 = img[yc0 * 28 + xc1];
        float g10 = img[yc1 * 28 + xc0];
        float g11 = img[yc1 * 28 + xc1];
        float val = g00 * (1.0f - wy) * (1.0f - wx) + g01 * (1.0f - wy) * wx
                  + g10 * wy * (1.0f - wx) + g11 * wy * wx;
        s1[q] = val;
    }
    __syncthreads();

    for (int q = t; q < 784; q += 256) {
        int py = q / 28, px = q - (q / 28) * 28;
        float val;
        if (rot) {
            float Yn = (2.0f * (float)py + 1.0f) / 28.0f - 1.0f;
            float Xn = (2.0f * (float)px + 1.0f) / 28.0f - 1.0f;
            float xs = cs * Xn - sn * Yn;
            float ys = sn * Xn + cs * Yn;
            float ix = ((xs + 1.0f) * 28.0f - 1.0f) / 2.0f;
            float iy = ((ys + 1.0f) * 28.0f - 1.0f) / 2.0f;
            float y0f = floorf(iy), x0f = floorf(ix);
            float wy = iy - y0f, wx = ix - x0f;
            int y0 = (int)y0f, x0 = (int)x0f;
            float g[2][2];
            #pragma unroll
            for (int dy = 0; dy < 2; ++dy) {
                #pragma unroll
                for (int dx = 0; dx < 2; ++dx) {
                    int yi = y0 + dy, xi = x0 + dx;
                    int yc = min(max(yi, 0), 27), xc = min(max(xi, 0), 27);
                    float vv = s1[yc * 28 + xc];
                    float valid = (yi >= 0 && yi < 28 && xi >= 0 && xi < 28) ? 1.0f : 0.0f;
                    g[dy][dx] = vv * valid;
                }
            }
            val = g[0][0] * (1.0f - wy) * (1.0f - wx) + g[0][1] * (1.0f - wy) * wx
                + g[1][0] * wy * (1.0f - wx) + g[1][1] * wy * wx;
        } else {
            val = s1[q];
        }

        if (cj) {
            float vc = fminf(fmaxf(val + bb, 0.0f), 1.0f);
            val = fminf(fmaxf((vc - 0.5f) * cc + 0.5f, 0.0f), 1.0f);
        }

        if (na) {
            int idx = i * 784 + q;
            uint32_t bits = rbits32(nk0, nk1, (uint32_t)idx);
            float f = u01_from_bits(bits);
            const float lo = -0.99999994f;
            float uu = f * 2.0f + lo;
            uu = fmaxf(lo, uu);
            float n = 1.4142135623730951f * erfinv_xla(uu);
            val = fminf(fmaxf(val + 0.05f * n, 0.0f), 1.0f);
        }

        AUG[i * 784 + q] = (val - 0.5f) / 0.5f;
    }
}

// conv12: conv1 MFMA (thread-per-pooled-position im2col, XOR-swizzled A1 units)
// + conv2 MFMA (wave-per-oc-tile). A1/pl1p alias one LDS buffer.
// A1 unit swizzle: su = u ^ ((u>>3)&7)  — permutes within each 8-unit group;
// write side u = t*8+(w*2+h) (u>>3 == t), read side recomputes identically.
__global__ __launch_bounds__(256) void conv12_kernel(
        const float* __restrict__ AUG,
        const float* __restrict__ W1, const float* __restrict__ b1,
        const ushort* __restrict__ W2gT, const float* __restrict__ b2,
        ushort* __restrict__ PL2) {
    int i = blockIdx.x, t = threadIdx.x;
    __shared__ __align__(16) ushort buf[12608];           // 1576 uint4 units
    __shared__ __align__(16) ushort w1sT[32 * 32];        // 2048 B  [oc][k]
    ushort* A1   = buf;
    ushort* pl1p = buf;

    {
        int q0 = t * 4;
        #pragma unroll
        for (int j = 0; j < 4; ++j) {
            int q = q0 + j;
            int oc = q >> 5, k = q & 31;
            w1sT[q] = (k < 9) ? f2bf(W1[oc * 9 + k]) : (ushort)0;
        }
    }

    const float* Ai = AUG + (size_t)i * 784;
    if (t < 196) {
        int py = t / 14, px = t - (t / 14) * 14;
        int ybase = 2 * py - 1, xbase = 2 * px - 1;
        uint32_t u[4][4];
        #pragma unroll
        for (int ry = 0; ry < 4; ++ry) {
            int yy = ybase + ry;
            bool yok = (unsigned)yy < 28u;
            const float* rowp = Ai + yy * 28;
            #pragma unroll
            for (int rx = 0; rx < 4; ++rx) {
                int xx = xbase + rx;
                float vv = (yok && (unsigned)xx < 28u) ? rowp[xx] : 0.0f;
                u[ry][rx] = (uint32_t)f2bf(vv);
            }
        }
        int tx = t & 7;
        #pragma unroll
        for (int w = 0; w < 4; ++w) {
            int dy = w >> 1, dx = w & 1;
            uint4 W0, W1v;
            W0.x = u[dy][dx]     | (u[dy][dx + 1] << 16);
            W0.y = u[dy][dx + 2] | (u[dy + 1][dx] << 16);
            W0.z = u[dy + 1][dx + 1] | (u[dy + 1][dx + 2] << 16);
            W0.w = u[dy + 2][dx]     | (u[dy + 2][dx + 1] << 16);
            W1v.x = u[dy + 2][dx + 2];
            W1v.y = 0; W1v.z = 0; W1v.w = 0;
            int u0 = t * 8 + w * 2;
            ((uint4*)A1)[u0 ^ tx]       = W0;
            ((uint4*)A1)[(u0 + 1) ^ tx] = W1v;
        }
    } else if (t < 204) {
        // zero the over-read tail units (row-783 lg>=2 granule reads land here)
        ((uint4*)A1)[1568 + (t - 196)] = uint4{0, 0, 0, 0};
    }
    __syncthreads();

    int l = t & 63, wv = t >> 6;
    int lr = l & 15, lg = l >> 4;

    float m0r[13], m1r[13];
    {
        bf16x8 bA = *(const bf16x8*)(w1sT + lr * 32 + lg * 8);
        bf16x8 bB = *(const bf16x8*)(w1sT + (16 + lr) * 32 + lg * 8);
        #pragma unroll
        for (int it = 0; it < 13; ++it) {
            int tt = wv + it * 4;
            if (tt < 49) {
                int u = (tt * 16 + lr) * 2 + lg;
                int su = u ^ ((u >> 3) & 7);
                bf16x8 af = *(const bf16x8*)(A1 + su * 8);
                f32x4 a0 = {0.0f, 0.0f, 0.0f, 0.0f};
                f32x4 a1acc = {0.0f, 0.0f, 0.0f, 0.0f};
                a0    = __builtin_amdgcn_mfma_f32_16x16x32_bf16(af, bA, a0, 0, 0, 0);
                a1acc = __builtin_amdgcn_mfma_f32_16x16x32_bf16(af, bB, a1acc, 0, 0, 0);
                m0r[it] = fmaxf(fmaxf(a0[0], a0[1]), fmaxf(a0[2], a0[3]));
                m1r[it] = fmaxf(fmaxf(a1acc[0], a1acc[1]), fmaxf(a1acc[2], a1acc[3]));
            }
        }
    }
    __syncthreads();

    for (int q = t; q < 1440; q += 256) ((uint4*)pl1p)[q] = uint4{0, 0, 0, 0};
    __syncthreads();

    {
        float bia0 = b1[lr], bia1 = b1[16 + lr];
        #pragma unroll
        for (int it = 0; it < 13; ++it) {
            int tt = wv + it * 4;
            if (tt < 49) {
                int pidx = tt * 4 + lg;
                int py = pidx / 14, px = pidx - py * 14;
                int base = ((py + 1) * 18 + (px + 1)) * 40;
                pl1p[base + lr]      = f2bf(fmaxf(m0r[it] + bia0, 0.0f));
                pl1p[base + 16 + lr] = f2bf(fmaxf(m1r[it] + bia1, 0.0f));
            }
        }
    }
    __syncthreads();

    {
        bf16x8 bfr[9];
        #pragma unroll
        for (int s = 0; s < 9; ++s)
            bfr[s] = *(const bf16x8*)(W2gT + (wv * 16 + lr) * 296 + s * 32 + lg * 8);
        float bias2 = b2[wv * 16 + lr];

        #pragma unroll
        for (int pyp = 0; pyp < 7; ++pyp) {
            int py0 = pyp * 2;
            bf16x8 f[4][3];
            #pragma unroll
            for (int j = 0; j < 4; ++j)
                #pragma unroll
                for (int kx = 0; kx < 3; ++kx)
                    f[j][kx] = *(const bf16x8*)(pl1p + ((py0 + j) * 18 + (lr + kx)) * 40 + lg * 8);
            f32x4 acc0 = {bias2, bias2, bias2, bias2};
            f32x4 acc1 = acc0;
            #pragma unroll
            for (int ky = 0; ky < 3; ++ky)
                #pragma unroll
                for (int kx = 0; kx < 3; ++kx) {
                    acc0 = __builtin_amdgcn_mfma_f32_16x16x32_bf16(f[ky][kx],     bfr[ky * 3 + kx], acc0, 0, 0, 0);
                    acc1 = __builtin_amdgcn_mfma_f32_16x16x32_bf16(f[ky + 1][kx], bfr[ky * 3 + kx], acc1, 0, 0, 0);
                }
            float v0 = fmaxf(fmaxf(fmaxf(acc0[0], acc0[1]), fmaxf(acc1[0], acc1[1])), 0.0f);
            float v1 = fmaxf(fmaxf(fmaxf(acc0[2], acc0[3]), fmaxf(acc1[2], acc1[3])), 0.0f);
            int px0 = lg * 2, px1 = px0 + 1;
            size_t base = (size_t)i * 3136 + (size_t)(pyp * 7) * 64 + wv * 16 + lr;
            PL2[base + (size_t)px0 * 64] = f2bf(v0);
            if (px1 < 7) PL2[base + (size_t)px1 * 64] = f2bf(v1);
        }
    }
}

// Generic bf16 GEMM: C[M][N] = A[M][K] * BT[N][K]^T + bias, 64x64 tile, BK=64,
// 4 waves (2x2), double-buffered swizzled LDS (R9/R12-proven version).
template<bool RELU, bool OUT_BF16>
__global__ __launch_bounds__(256) void gemm_bt_kernel(
        const ushort* __restrict__ A, const ushort* __restrict__ BT,
        const float* __restrict__ bias, void* __restrict__ Cout,
        int M, int N, int K) {
    __shared__ __align__(16) ushort lds[2][2][4096];   // [buf][A/B][64*64] bf16
    int t = threadIdx.x;
    int w = t >> 6, l = t & 63;
    int lr = l & 15, lc = l >> 4;
    int wm = w >> 1, wn = w & 1;
    int bm = blockIdx.x, bn = blockIdx.y;
    int NKt = K >> 6;

    const ushort* Ab = A + (size_t)bm * 64 * K;
    const ushort* Bb = BT + (size_t)bn * 64 * K;

    int r0 = t >> 3, s0 = t & 7;
    int c1i = t + 256;
    int r1 = c1i >> 3, s1 = c1i & 7;
    int d0 = r0 * 8 + (s0 ^ (r0 & 7));
    int d1 = r1 * 8 + (s1 ^ (r1 & 7));

    f32x4 acc[2][2] = {};

    uint4 tA0, tA1, tB0, tB1;
    #define GLOAD(kt) do { \
        tA0 = *(const uint4*)(Ab + (size_t)r0 * K + (kt) * 64 + s0 * 8); \
        tA1 = *(const uint4*)(Ab + (size_t)r1 * K + (kt) * 64 + s1 * 8); \
        tB0 = *(const uint4*)(Bb + (size_t)r0 * K + (kt) * 64 + s0 * 8); \
        tB1 = *(const uint4*)(Bb + (size_t)r1 * K + (kt) * 64 + s1 * 8); } while (0)
    #define LWRITE(bufi) do { \
        ((uint4*)lds[bufi][0])[d0] = tA0; ((uint4*)lds[bufi][0])[d1] = tA1; \
        ((uint4*)lds[bufi][1])[d0] = tB0; ((uint4*)lds[bufi][1])[d1] = tB1; } while (0)

    GLOAD(0); LWRITE(0);
    int buf = 0;
    for (int kt = 0; kt < NKt; ++kt) {
        __syncthreads();
        if (kt + 1 < NKt) GLOAD(kt + 1);
        const ushort* Al = lds[buf][0];
        const ushort* Bl = lds[buf][1];
        #pragma unroll
        for (int ks = 0; ks < 2; ++ks) {
            bf16x8 af[2], bg[2];
            #pragma unroll
            for (int mt = 0; mt < 2; ++mt) {
                int row = wm * 32 + mt * 16 + lr;
                int unit = row * 8 + ((ks * 4 + lc) ^ (row & 7));
                af[mt] = *(const bf16x8*)(Al + unit * 8);
            }
            #pragma unroll
            for (int nt = 0; nt < 2; ++nt) {
                int row = wn * 32 + nt * 16 + lr;
                int unit = row * 8 + ((ks * 4 + lc) ^ (row & 7));
                bg[nt] = *(const bf16x8*)(Bl + unit * 8);
            }
            #pragma unroll
            for (int mt = 0; mt < 2; ++mt)
                #pragma unroll
                for (int nt = 0; nt < 2; ++nt)
                    acc[mt][nt] = __builtin_amdgcn_mfma_f32_16x16x32_bf16(af[mt], bg[nt], acc[mt][nt], 0, 0, 0);
        }
        if (kt + 1 < NKt) LWRITE(buf ^ 1);
        buf ^= 1;
    }

    #pragma unroll
    for (int nt = 0; nt < 2; ++nt) {
        int gcol = bn * 64 + wn * 32 + nt * 16 + lr;
        float bv = bias[gcol];
        #pragma unroll
        for (int mt = 0; mt < 2; ++mt) {
            #pragma unroll
            for (int rg = 0; rg < 4; ++rg) {
                int grow = bm * 64 + wm * 32 + mt * 16 + lc * 4 + rg;
                float vv = acc[mt][nt][rg] + bv;
                if (RELU) vv = fmaxf(vv, 0.0f);
                if (OUT_BF16) ((ushort*)Cout)[(size_t)grow * N + gcol] = f2bf(vv);
                else          ((float*)Cout)[(size_t)grow * N + gcol] = vv;
            }
        }
    }
    #undef GLOAD
    #undef LWRITE
}

// ---------------- launch ----------------
extern "C" void kernel_launch(void* const* d_in, const int* in_sizes, int n_in,
                              void* d_out, int out_size, void* d_ws, size_t ws_size,
                              hipStream_t stream) {
    const float* x   = (const float*)d_in[0];
    const float* W1  = (const float*)d_in[1];
    const float* b1  = (const float*)d_in[2];
    const float* W2  = (const float*)d_in[3];
    const float* b2  = (const float*)d_in[4];
    const float* Wf  = (const float*)d_in[5];
    const float* bf  = (const float*)d_in[6];
    const float* Wp1 = (const float*)d_in[7];
    const float* bp1 = (const float*)d_in[8];
    const float* Wp2 = (const float*)d_in[9];
    const float* bp2 = (const float*)d_in[10];

    float* ws     = (float*)d_ws;
    float* P      = ws + P_OFF;
    uint32_t* NK  = (uint32_t*)(ws + NK_OFF);
    ushort* W2gT  = (ushort*)(ws + W2GT_OFF);
    ushort* WfB   = (ushort*)(ws + WFB_OFF);
    ushort* Wp1B  = (ushort*)(ws + WP1B_OFF);
    ushort* Wp2B  = (ushort*)(ws + WP2B_OFF);
    float* AUG    = ws + AUG_OFF;
    ushort* PL2   = (ushort*)(ws + PL2_OFF);
    ushort* Hb    = (ushort*)(ws + H_OFF);
    ushort* P1    = (ushort*)(ws + AUG_OFF);   // alias: AUG dead before proj1 writes
    float* out    = (float*)d_out;

    param_kernel<<<32, 256, 0, stream>>>(P, NK);
    wprep_w2<<<74, 256, 0, stream>>>(W2, W2gT);
    wprep_wf<<<6272, 256, 0, stream>>>(Wf, WfB);
    wprep_cast<<<1024, 256, 0, stream>>>(Wp1, Wp1B, 512 * 512);
    wprep_cast<<<256, 256, 0, stream>>>(Wp2, Wp2B, 128 * 512);

    for (int v = 0; v < 2; ++v) {
        augment_kernel<<<4096, 256, 0, stream>>>(x, P, NK, AUG, v);
        conv12_kernel<<<4096, 256, 0, stream>>>(AUG, W1, b1, W2gT, b2, PL2);
        gemm_bt_kernel<false, true><<<dim3(64, 8), 256, 0, stream>>>(
            PL2, WfB, bf, Hb, 4096, 512, 3136);
        gemm_bt_kernel<true, true><<<dim3(64, 8), 256, 0, stream>>>(
            Hb, Wp1B, bp1, P1, 4096, 512, 512);
        gemm_bt_kernel<false, false><<<dim3(64, 2), 256, 0, stream>>>(
            P1, Wp2B, bp2, out + (size_t)v * 4096 * 128, 4096, 128, 512);
    }
}

// Round 16
// 231.303 us; speedup vs baseline: 1.7748x; 1.1111x over previous
//
#include <hip/hip_runtime.h>
#include <stdint.h>
#include <math.h>

typedef __attribute__((ext_vector_type(8))) short bf16x8;
typedef __attribute__((ext_vector_type(4))) float f32x4;

__device__ __forceinline__ ushort f2bf(float f) {      // RTNE, finite inputs
    uint32_t u = __float_as_uint(f);
    u += 0x7fffu + ((u >> 16) & 1u);
    return (ushort)(u >> 16);
}

// ---------------- Threefry-2x32 (JAX-exact, partitionable mode) ----------------
__device__ __forceinline__ uint32_t rotl32(uint32_t v, int r) {
    return (v << r) | (v >> (32 - r));
}

__device__ __forceinline__ void threefry(uint32_t k0, uint32_t k1,
                                         uint32_t c0, uint32_t c1,
                                         uint32_t& o0, uint32_t& o1) {
    uint32_t ks2 = k0 ^ k1 ^ 0x1BD11BDAu;
    uint32_t x0 = c0 + k0, x1 = c1 + k1;
    x0 += x1; x1 = rotl32(x1, 13); x1 ^= x0;
    x0 += x1; x1 = rotl32(x1, 15); x1 ^= x0;
    x0 += x1; x1 = rotl32(x1, 26); x1 ^= x0;
    x0 += x1; x1 = rotl32(x1,  6); x1 ^= x0;
    x0 += k1;  x1 += ks2 + 1u;
    x0 += x1; x1 = rotl32(x1, 17); x1 ^= x0;
    x0 += x1; x1 = rotl32(x1, 29); x1 ^= x0;
    x0 += x1; x1 = rotl32(x1, 16); x1 ^= x0;
    x0 += x1; x1 = rotl32(x1, 24); x1 ^= x0;
    x0 += ks2; x1 += k0 + 2u;
    x0 += x1; x1 = rotl32(x1, 13); x1 ^= x0;
    x0 += x1; x1 = rotl32(x1, 15); x1 ^= x0;
    x0 += x1; x1 = rotl32(x1, 26); x1 ^= x0;
    x0 += x1; x1 = rotl32(x1,  6); x1 ^= x0;
    x0 += k0;  x1 += k1 + 3u;
    x0 += x1; x1 = rotl32(x1, 17); x1 ^= x0;
    x0 += x1; x1 = rotl32(x1, 29); x1 ^= x0;
    x0 += x1; x1 = rotl32(x1, 16); x1 ^= x0;
    x0 += x1; x1 = rotl32(x1, 24); x1 ^= x0;
    x0 += k1;  x1 += ks2 + 4u;
    x0 += x1; x1 = rotl32(x1, 13); x1 ^= x0;
    x0 += x1; x1 = rotl32(x1, 15); x1 ^= x0;
    x0 += x1; x1 = rotl32(x1, 26); x1 ^= x0;
    x0 += x1; x1 = rotl32(x1,  6); x1 ^= x0;
    x0 += ks2; x1 += k0 + 5u;
    o0 = x0; o1 = x1;
}

__device__ __forceinline__ uint32_t rbits32(uint32_t k0, uint32_t k1, uint32_t idx) {
    uint32_t o0, o1;
    threefry(k0, k1, 0u, idx, o0, o1);
    return o0 ^ o1;
}

__device__ __forceinline__ float u01_from_bits(uint32_t bits) {
    return __uint_as_float((bits >> 9) | 0x3f800000u) - 1.0f;
}

__device__ float erfinv_xla(float x) {
    #pragma clang fp contract(off)
    float w = -log1pf(-x * x);
    float p;
    if (w < 5.0f) {
        w = w - 2.5f;
        p = 2.81022636e-08f;
        p = 3.43273939e-07f + p * w;
        p = -3.5233877e-06f + p * w;
        p = -4.39150654e-06f + p * w;
        p = 0.00021858087f + p * w;
        p = -0.00125372503f + p * w;
        p = -0.00417768164f + p * w;
        p = 0.246640727f + p * w;
        p = 1.50140941f + p * w;
    } else {
        w = sqrtf(w) - 3.0f;
        p = -0.000200214257f;
        p = 0.000100950558f + p * w;
        p = 0.00134934322f + p * w;
        p = -0.00367342844f + p * w;
        p = 0.00573950773f + p * w;
        p = -0.0076224613f + p * w;
        p = 0.00943887047f + p * w;
        p = 1.00167406f + p * w;
        p = 2.83297682f + p * w;
    }
    return p * x;
}

// ---------------- workspace layout (float offsets) ----------------
// common prefix
#define P_OFF      0           // 8192*12
#define NK_OFF     98304       // 4 u32 (16 f reserved)
#define W2GT_OFF   98320       // 64*296 bf16 = 9472 f
#define WFB_OFF    107792      // 512*3136 bf16 = 802816 f
#define WP1B_OFF   910608      // 512*512 bf16 = 131072 f
#define WP2B_OFF   1041680     // 128*512 bf16 = 32768 f
#define DATA_OFF   1074448
// per-view mode (R15-proven, 47.0 MB):
//   AUG 4096*784 f32 (3211264 f), PL2 4096*3136 bf16 (6422528 f), H (524288 f... see code)
// batched mode (89.8 MB): AUG8 8192*784 f32, PL28 8192*3136 bf16, H8 8192*512 bf16
#define BATCH_FLOATS 22439184ull   // prefix + AUG8 + PL28 + H8

// ---------------- kernels ----------------
__global__ void param_kernel(float* __restrict__ P, uint32_t* __restrict__ NK) {
    #pragma clang fp contract(off)
    int gid = blockIdx.x * blockDim.x + threadIdx.x;
    if (gid >= 8192) return;
    int v = gid >> 12;
    int i = gid & 4095;

    uint32_t kv0, kv1;
    threefry(0u, 42u, 0u, (uint32_t)v, kv0, kv1);

    uint32_t sk0[11], sk1[11];
    #pragma unroll
    for (int j = 0; j < 11; ++j) threefry(kv0, kv1, 0u, (uint32_t)j, sk0[j], sk1[j]);

    float u[10];
    #pragma unroll
    for (int j = 0; j < 10; ++j) u[j] = u01_from_bits(rbits32(sk0[j], sk1[j], (uint32_t)i));

    float crop = floorf(28.0f * (0.7f + 0.3f * u[0]));
    float top  = floorf((28.0f - crop) * u[1]);
    float left = floorf((28.0f - crop) * u[2]);
    float flip = (u[3] < 0.5f) ? 1.0f : 0.0f;
    float rot  = (u[4] < 0.8f) ? 1.0f : 0.0f;
    float rad  = ((20.0f * u[5] - 10.0f) * 3.14159274101257324f) / 180.0f;
    float cj   = (u[6] < 0.8f) ? 1.0f : 0.0f;
    float bb   = 0.2f * u[7] - 0.1f;
    float cc   = 0.8f + 0.4f * u[8];
    float na   = (u[9] < 0.5f) ? 1.0f : 0.0f;

    float* p = P + gid * 12;
    p[0] = crop; p[1] = top; p[2] = left; p[3] = flip; p[4] = rot;
    p[5] = rad;  p[6] = cj;  p[7] = bb;   p[8] = cc;   p[9] = na;
    p[10] = cosf(rad); p[11] = sinf(rad);

    if (i == 0) { NK[v * 2] = sk0[10]; NK[v * 2 + 1] = sk1[10]; }
}

// W2 (64,32,3,3) -> W2gT[oc][k=(ky*3+kx)*32+ic], padded row stride 296, bf16
__global__ void wprep_w2(const float* __restrict__ W2, ushort* __restrict__ W2gT) {
    int idx = blockIdx.x * 256 + threadIdx.x;
    if (idx >= 64 * 296) return;
    int oc = idx / 296, k = idx % 296;
    float v = 0.0f;
    if (k < 288) {
        int s = k >> 5, ic = k & 31;
        int ky = s / 3, kx = s % 3;
        v = W2[((oc * 32 + ic) * 3 + ky) * 3 + kx];
    }
    W2gT[idx] = f2bf(v);
}

// Wf (512, 3136=oc*49+pos) -> WfB[n][k'=pos*64+oc] bf16
__global__ void wprep_wf(const float* __restrict__ Wf, ushort* __restrict__ WfB) {
    int idx = blockIdx.x * 256 + threadIdx.x;
    if (idx >= 512 * 3136) return;
    int n = idx / 3136, kp = idx % 3136;
    int pos = kp >> 6, oc = kp & 63;
    WfB[idx] = f2bf(Wf[n * 3136 + oc * 49 + pos]);
}

__global__ void wprep_cast(const float* __restrict__ src, ushort* __restrict__ dst, int n) {
    int idx = blockIdx.x * 256 + threadIdx.x;
    if (idx < n) dst[idx] = f2bf(src[idx]);
}

// Block-per-image augment (R12/R15-proven). li = blockIdx.x indexes the AUG
// buffer; global image id r = base + li (v = r>>12, i = r&4095).
__global__ __launch_bounds__(256) void augment_kernel(const float* __restrict__ x,
                                                      const float* __restrict__ P,
                                                      const uint32_t* __restrict__ NK,
                                                      float* __restrict__ AUG, int base) {
    #pragma clang fp contract(off)
    int li = blockIdx.x;
    int r = base + li;
    int v = r >> 12, i = r & 4095;
    int t = threadIdx.x;
    __shared__ float img[784];
    __shared__ float s1[784];
    __shared__ float srctab[28];

    const float* p = P + r * 12;
    float crop = p[0], top = p[1], left = p[2];
    int flip = (p[3] != 0.0f);
    int rot  = (p[4] != 0.0f);
    int cj = (p[6] != 0.0f);
    float bb = p[7], cc = p[8];
    int na = (p[9] != 0.0f);
    float cs = p[10], sn = p[11];
    uint32_t nk0 = NK[v * 2], nk1 = NK[v * 2 + 1];

    for (int q = t; q < 784; q += 256) img[q] = x[i * 784 + q];
    if (t < 28) {
        float j = (float)t + 0.5f;
        float s = j * crop / 28.0f - 0.5f;
        srctab[t] = fminf(fmaxf(s, 0.0f), crop - 1.0f);
    }
    __syncthreads();

    for (int q = t; q < 784; q += 256) {
        int py = q / 28, px = q - (q / 28) * 28;
        int sxcol = flip ? (27 - px) : px;
        float yy = srctab[py] + top;
        float xx = srctab[sxcol] + left;
        float y0f = floorf(yy), x0f = floorf(xx);
        float wy = yy - y0f, wx = xx - x0f;
        int y0 = (int)y0f, x0 = (int)x0f;

        int yc0 = min(max(y0, 0), 27),     xc0 = min(max(x0, 0), 27);
        int yc1 = min(max(y0 + 1, 0), 27), xc1 = min(max(x0 + 1, 0), 27);
        float g00 = img[yc0 * 28 + xc0];
        float g01 = img[yc0 * 28 + xc1];
        float g10 = img[yc1 * 28 + xc0];
        float g11 = img[yc1 * 28 + xc1];
        float val = g00 * (1.0f - wy) * (1.0f - wx) + g01 * (1.0f - wy) * wx
                  + g10 * wy * (1.0f - wx) + g11 * wy * wx;
        s1[q] = val;
    }
    __syncthreads();

    for (int q = t; q < 784; q += 256) {
        int py = q / 28, px = q - (q / 28) * 28;
        float val;
        if (rot) {
            float Yn = (2.0f * (float)py + 1.0f) / 28.0f - 1.0f;
            float Xn = (2.0f * (float)px + 1.0f) / 28.0f - 1.0f;
            float xs = cs * Xn - sn * Yn;
            float ys = sn * Xn + cs * Yn;
            float ix = ((xs + 1.0f) * 28.0f - 1.0f) / 2.0f;
            float iy = ((ys + 1.0f) * 28.0f - 1.0f) / 2.0f;
            float y0f = floorf(iy), x0f = floorf(ix);
            float wy = iy - y0f, wx = ix - x0f;
            int y0 = (int)y0f, x0 = (int)x0f;
            float g[2][2];
            #pragma unroll
            for (int dy = 0; dy < 2; ++dy) {
                #pragma unroll
                for (int dx = 0; dx < 2; ++dx) {
                    int yi = y0 + dy, xi = x0 + dx;
                    int yc = min(max(yi, 0), 27), xc = min(max(xi, 0), 27);
                    float vv = s1[yc * 28 + xc];
                    float valid = (yi >= 0 && yi < 28 && xi >= 0 && xi < 28) ? 1.0f : 0.0f;
                    g[dy][dx] = vv * valid;
                }
            }
            val = g[0][0] * (1.0f - wy) * (1.0f - wx) + g[0][1] * (1.0f - wy) * wx
                + g[1][0] * wy * (1.0f - wx) + g[1][1] * wy * wx;
        } else {
            val = s1[q];
        }

        if (cj) {
            float vc = fminf(fmaxf(val + bb, 0.0f), 1.0f);
            val = fminf(fmaxf((vc - 0.5f) * cc + 0.5f, 0.0f), 1.0f);
        }

        if (na) {
            int idx = i * 784 + q;
            uint32_t bits = rbits32(nk0, nk1, (uint32_t)idx);
            float f = u01_from_bits(bits);
            const float lo = -0.99999994f;
            float uu = f * 2.0f + lo;
            uu = fmaxf(lo, uu);
            float n = 1.4142135623730951f * erfinv_xla(uu);
            val = fminf(fmaxf(val + 0.05f * n, 0.0f), 1.0f);
        }

        AUG[li * 784 + q] = (val - 0.5f) / 0.5f;
    }
}

// conv12 (R15-proven): conv1 MFMA (XOR-swizzled A1) + conv2 MFMA
// (wave-per-oc-tile). Index-agnostic: block li reads AUG[li], writes PL2[li].
__global__ __launch_bounds__(256) void conv12_kernel(
        const float* __restrict__ AUG,
        const float* __restrict__ W1, const float* __restrict__ b1,
        const ushort* __restrict__ W2gT, const float* __restrict__ b2,
        ushort* __restrict__ PL2) {
    int i = blockIdx.x, t = threadIdx.x;
    __shared__ __align__(16) ushort buf[12608];           // 1576 uint4 units
    __shared__ __align__(16) ushort w1sT[32 * 32];        // 2048 B  [oc][k]
    ushort* A1   = buf;
    ushort* pl1p = buf;

    {
        int q0 = t * 4;
        #pragma unroll
        for (int j = 0; j < 4; ++j) {
            int q = q0 + j;
            int oc = q >> 5, k = q & 31;
            w1sT[q] = (k < 9) ? f2bf(W1[oc * 9 + k]) : (ushort)0;
        }
    }

    const float* Ai = AUG + (size_t)i * 784;
    if (t < 196) {
        int py = t / 14, px = t - (t / 14) * 14;
        int ybase = 2 * py - 1, xbase = 2 * px - 1;
        uint32_t u[4][4];
        #pragma unroll
        for (int ry = 0; ry < 4; ++ry) {
            int yy = ybase + ry;
            bool yok = (unsigned)yy < 28u;
            const float* rowp = Ai + yy * 28;
            #pragma unroll
            for (int rx = 0; rx < 4; ++rx) {
                int xx = xbase + rx;
                float vv = (yok && (unsigned)xx < 28u) ? rowp[xx] : 0.0f;
                u[ry][rx] = (uint32_t)f2bf(vv);
            }
        }
        int tx = t & 7;
        #pragma unroll
        for (int w = 0; w < 4; ++w) {
            int dy = w >> 1, dx = w & 1;
            uint4 W0, W1v;
            W0.x = u[dy][dx]     | (u[dy][dx + 1] << 16);
            W0.y = u[dy][dx + 2] | (u[dy + 1][dx] << 16);
            W0.z = u[dy + 1][dx + 1] | (u[dy + 1][dx + 2] << 16);
            W0.w = u[dy + 2][dx]     | (u[dy + 2][dx + 1] << 16);
            W1v.x = u[dy + 2][dx + 2];
            W1v.y = 0; W1v.z = 0; W1v.w = 0;
            int u0 = t * 8 + w * 2;
            ((uint4*)A1)[u0 ^ tx]       = W0;
            ((uint4*)A1)[(u0 + 1) ^ tx] = W1v;
        }
    } else if (t < 204) {
        ((uint4*)A1)[1568 + (t - 196)] = uint4{0, 0, 0, 0};
    }
    __syncthreads();

    int l = t & 63, wv = t >> 6;
    int lr = l & 15, lg = l >> 4;

    float m0r[13], m1r[13];
    {
        bf16x8 bA = *(const bf16x8*)(w1sT + lr * 32 + lg * 8);
        bf16x8 bB = *(const bf16x8*)(w1sT + (16 + lr) * 32 + lg * 8);
        #pragma unroll
        for (int it = 0; it < 13; ++it) {
            int tt = wv + it * 4;
            if (tt < 49) {
                int u = (tt * 16 + lr) * 2 + lg;
                int su = u ^ ((u >> 3) & 7);
                bf16x8 af = *(const bf16x8*)(A1 + su * 8);
                f32x4 a0 = {0.0f, 0.0f, 0.0f, 0.0f};
                f32x4 a1acc = {0.0f, 0.0f, 0.0f, 0.0f};
                a0    = __builtin_amdgcn_mfma_f32_16x16x32_bf16(af, bA, a0, 0, 0, 0);
                a1acc = __builtin_amdgcn_mfma_f32_16x16x32_bf16(af, bB, a1acc, 0, 0, 0);
                m0r[it] = fmaxf(fmaxf(a0[0], a0[1]), fmaxf(a0[2], a0[3]));
                m1r[it] = fmaxf(fmaxf(a1acc[0], a1acc[1]), fmaxf(a1acc[2], a1acc[3]));
            }
        }
    }
    __syncthreads();

    for (int q = t; q < 1440; q += 256) ((uint4*)pl1p)[q] = uint4{0, 0, 0, 0};
    __syncthreads();

    {
        float bia0 = b1[lr], bia1 = b1[16 + lr];
        #pragma unroll
        for (int it = 0; it < 13; ++it) {
            int tt = wv + it * 4;
            if (tt < 49) {
                int pidx = tt * 4 + lg;
                int py = pidx / 14, px = pidx - py * 14;
                int base = ((py + 1) * 18 + (px + 1)) * 40;
                pl1p[base + lr]      = f2bf(fmaxf(m0r[it] + bia0, 0.0f));
                pl1p[base + 16 + lr] = f2bf(fmaxf(m1r[it] + bia1, 0.0f));
            }
        }
    }
    __syncthreads();

    {
        bf16x8 bfr[9];
        #pragma unroll
        for (int s = 0; s < 9; ++s)
            bfr[s] = *(const bf16x8*)(W2gT + (wv * 16 + lr) * 296 + s * 32 + lg * 8);
        float bias2 = b2[wv * 16 + lr];

        #pragma unroll
        for (int pyp = 0; pyp < 7; ++pyp) {
            int py0 = pyp * 2;
            bf16x8 f[4][3];
            #pragma unroll
            for (int j = 0; j < 4; ++j)
                #pragma unroll
                for (int kx = 0; kx < 3; ++kx)
                    f[j][kx] = *(const bf16x8*)(pl1p + ((py0 + j) * 18 + (lr + kx)) * 40 + lg * 8);
            f32x4 acc0 = {bias2, bias2, bias2, bias2};
            f32x4 acc1 = acc0;
            #pragma unroll
            for (int ky = 0; ky < 3; ++ky)
                #pragma unroll
                for (int kx = 0; kx < 3; ++kx) {
                    acc0 = __builtin_amdgcn_mfma_f32_16x16x32_bf16(f[ky][kx],     bfr[ky * 3 + kx], acc0, 0, 0, 0);
                    acc1 = __builtin_amdgcn_mfma_f32_16x16x32_bf16(f[ky + 1][kx], bfr[ky * 3 + kx], acc1, 0, 0, 0);
                }
            float v0 = fmaxf(fmaxf(fmaxf(acc0[0], acc0[1]), fmaxf(acc1[0], acc1[1])), 0.0f);
            float v1 = fmaxf(fmaxf(fmaxf(acc0[2], acc0[3]), fmaxf(acc1[2], acc1[3])), 0.0f);
            int px0 = lg * 2, px1 = px0 + 1;
            size_t base = (size_t)i * 3136 + (size_t)(pyp * 7) * 64 + wv * 16 + lr;
            PL2[base + (size_t)px0 * 64] = f2bf(v0);
            if (px1 < 7) PL2[base + (size_t)px1 * 64] = f2bf(v1);
        }
    }
}

// Generic bf16 GEMM: C[M][N] = A[M][K] * BT[N][K]^T + bias, 64x64 tile, BK=64,
// 4 waves (2x2), double-buffered swizzled LDS (R9/R12/R15-proven).
template<bool RELU, bool OUT_BF16>
__global__ __launch_bounds__(256) void gemm_bt_kernel(
        const ushort* __restrict__ A, const ushort* __restrict__ BT,
        const float* __restrict__ bias, void* __restrict__ Cout,
        int M, int N, int K) {
    __shared__ __align__(16) ushort lds[2][2][4096];   // [buf][A/B][64*64] bf16
    int t = threadIdx.x;
    int w = t >> 6, l = t & 63;
    int lr = l & 15, lc = l >> 4;
    int wm = w >> 1, wn = w & 1;
    int bm = blockIdx.x, bn = blockIdx.y;
    int NKt = K >> 6;

    const ushort* Ab = A + (size_t)bm * 64 * K;
    const ushort* Bb = BT + (size_t)bn * 64 * K;

    int r0 = t >> 3, s0 = t & 7;
    int c1i = t + 256;
    int r1 = c1i >> 3, s1 = c1i & 7;
    int d0 = r0 * 8 + (s0 ^ (r0 & 7));
    int d1 = r1 * 8 + (s1 ^ (r1 & 7));

    f32x4 acc[2][2] = {};

    uint4 tA0, tA1, tB0, tB1;
    #define GLOAD(kt) do { \
        tA0 = *(const uint4*)(Ab + (size_t)r0 * K + (kt) * 64 + s0 * 8); \
        tA1 = *(const uint4*)(Ab + (size_t)r1 * K + (kt) * 64 + s1 * 8); \
        tB0 = *(const uint4*)(Bb + (size_t)r0 * K + (kt) * 64 + s0 * 8); \
        tB1 = *(const uint4*)(Bb + (size_t)r1 * K + (kt) * 64 + s1 * 8); } while (0)
    #define LWRITE(bufi) do { \
        ((uint4*)lds[bufi][0])[d0] = tA0; ((uint4*)lds[bufi][0])[d1] = tA1; \
        ((uint4*)lds[bufi][1])[d0] = tB0; ((uint4*)lds[bufi][1])[d1] = tB1; } while (0)

    GLOAD(0); LWRITE(0);
    int buf = 0;
    for (int kt = 0; kt < NKt; ++kt) {
        __syncthreads();
        if (kt + 1 < NKt) GLOAD(kt + 1);
        const ushort* Al = lds[buf][0];
        const ushort* Bl = lds[buf][1];
        #pragma unroll
        for (int ks = 0; ks < 2; ++ks) {
            bf16x8 af[2], bg[2];
            #pragma unroll
            for (int mt = 0; mt < 2; ++mt) {
                int row = wm * 32 + mt * 16 + lr;
                int unit = row * 8 + ((ks * 4 + lc) ^ (row & 7));
                af[mt] = *(const bf16x8*)(Al + unit * 8);
            }
            #pragma unroll
            for (int nt = 0; nt < 2; ++nt) {
                int row = wn * 32 + nt * 16 + lr;
                int unit = row * 8 + ((ks * 4 + lc) ^ (row & 7));
                bg[nt] = *(const bf16x8*)(Bl + unit * 8);
            }
            #pragma unroll
            for (int mt = 0; mt < 2; ++mt)
                #pragma unroll
                for (int nt = 0; nt < 2; ++nt)
                    acc[mt][nt] = __builtin_amdgcn_mfma_f32_16x16x32_bf16(af[mt], bg[nt], acc[mt][nt], 0, 0, 0);
        }
        if (kt + 1 < NKt) LWRITE(buf ^ 1);
        buf ^= 1;
    }

    #pragma unroll
    for (int nt = 0; nt < 2; ++nt) {
        int gcol = bn * 64 + wn * 32 + nt * 16 + lr;
        float bv = bias[gcol];
        #pragma unroll
        for (int mt = 0; mt < 2; ++mt) {
            #pragma unroll
            for (int rg = 0; rg < 4; ++rg) {
                int grow = bm * 64 + wm * 32 + mt * 16 + lc * 4 + rg;
                float vv = acc[mt][nt][rg] + bv;
                if (RELU) vv = fmaxf(vv, 0.0f);
                if (OUT_BF16) ((ushort*)Cout)[(size_t)grow * N + gcol] = f2bf(vv);
                else          ((float*)Cout)[(size_t)grow * N + gcol] = vv;
            }
        }
    }
    #undef GLOAD
    #undef LWRITE
}

// ---------------- launch ----------------
extern "C" void kernel_launch(void* const* d_in, const int* in_sizes, int n_in,
                              void* d_out, int out_size, void* d_ws, size_t ws_size,
                              hipStream_t stream) {
    const float* x   = (const float*)d_in[0];
    const float* W1  = (const float*)d_in[1];
    const float* b1  = (const float*)d_in[2];
    const float* W2  = (const float*)d_in[3];
    const float* b2  = (const float*)d_in[4];
    const float* Wf  = (const float*)d_in[5];
    const float* bf  = (const float*)d_in[6];
    const float* Wp1 = (const float*)d_in[7];
    const float* bp1 = (const float*)d_in[8];
    const float* Wp2 = (const float*)d_in[9];
    const float* bp2 = (const float*)d_in[10];

    float* ws     = (float*)d_ws;
    float* P      = ws + P_OFF;
    uint32_t* NK  = (uint32_t*)(ws + NK_OFF);
    ushort* W2gT  = (ushort*)(ws + W2GT_OFF);
    ushort* WfB   = (ushort*)(ws + WFB_OFF);
    ushort* Wp1B  = (ushort*)(ws + WP1B_OFF);
    ushort* Wp2B  = (ushort*)(ws + WP2B_OFF);
    float* out    = (float*)d_out;

    param_kernel<<<32, 256, 0, stream>>>(P, NK);
    wprep_w2<<<74, 256, 0, stream>>>(W2, W2gT);
    wprep_wf<<<6272, 256, 0, stream>>>(Wf, WfB);
    wprep_cast<<<1024, 256, 0, stream>>>(Wp1, Wp1B, 512 * 512);
    wprep_cast<<<256, 256, 0, stream>>>(Wp2, Wp2B, 128 * 512);

    if (ws_size >= BATCH_FLOATS * 4ull) {
        // -------- batched: both views in one launch set (GEMMs at 2x grid) ----
        float* AUG8  = ws + DATA_OFF;                        // 8192*784 f32
        ushort* PL28 = (ushort*)(ws + DATA_OFF + 6422528);   // 8192*3136 bf16
        ushort* H8   = (ushort*)(ws + DATA_OFF + 19267584);  // 8192*512 bf16
        ushort* P18  = (ushort*)AUG8;                        // alias: AUG dead after conv12

        augment_kernel<<<8192, 256, 0, stream>>>(x, P, NK, AUG8, 0);
        conv12_kernel<<<8192, 256, 0, stream>>>(AUG8, W1, b1, W2gT, b2, PL28);
        gemm_bt_kernel<false, true><<<dim3(128, 8), 256, 0, stream>>>(
            PL28, WfB, bf, H8, 8192, 512, 3136);
        gemm_bt_kernel<true, true><<<dim3(128, 8), 256, 0, stream>>>(
            H8, Wp1B, bp1, P18, 8192, 512, 512);
        gemm_bt_kernel<false, false><<<dim3(128, 2), 256, 0, stream>>>(
            P18, Wp2B, bp2, out, 8192, 128, 512);
    } else {
        // -------- per-view fallback (exact R15 schedule) ----------------------
        float* AUG  = ws + DATA_OFF;                         // 4096*784 f32
        ushort* PL2 = (ushort*)(ws + DATA_OFF + 3211264);    // 4096*3136 bf16
        ushort* Hb  = (ushort*)(ws + DATA_OFF + 9633792);    // 4096*512 bf16
        ushort* P1  = (ushort*)AUG;

        for (int v = 0; v < 2; ++v) {
            augment_kernel<<<4096, 256, 0, stream>>>(x, P, NK, AUG, v * 4096);
            conv12_kernel<<<4096, 256, 0, stream>>>(AUG, W1, b1, W2gT, b2, PL2);
            gemm_bt_kernel<false, true><<<dim3(64, 8), 256, 0, stream>>>(
                PL2, WfB, bf, Hb, 4096, 512, 3136);
            gemm_bt_kernel<true, true><<<dim3(64, 8), 256, 0, stream>>>(
                Hb, Wp1B, bp1, P1, 4096, 512, 512);
            gemm_bt_kernel<false, false><<<dim3(64, 2), 256, 0, stream>>>(
                P1, Wp2B, bp2, out + (size_t)v * 4096 * 128, 4096, 128, 512);
        }
    }
}

// Round 17
// 228.266 us; speedup vs baseline: 1.7984x; 1.0133x over previous
//
#include <hip/hip_runtime.h>
#include <stdint.h>
#include <math.h>

typedef __attribute__((ext_vector_type(8))) short bf16x8;
typedef __attribute__((ext_vector_type(4))) float f32x4;

__device__ __forceinline__ ushort f2bf(float f) {      // RTNE, finite inputs
    uint32_t u = __float_as_uint(f);
    u += 0x7fffu + ((u >> 16) & 1u);
    return (ushort)(u >> 16);
}

// ---------------- Threefry-2x32 (JAX-exact, partitionable mode) ----------------
__device__ __forceinline__ uint32_t rotl32(uint32_t v, int r) {
    return (v << r) | (v >> (32 - r));
}

__device__ __forceinline__ void threefry(uint32_t k0, uint32_t k1,
                                         uint32_t c0, uint32_t c1,
                                         uint32_t& o0, uint32_t& o1) {
    uint32_t ks2 = k0 ^ k1 ^ 0x1BD11BDAu;
    uint32_t x0 = c0 + k0, x1 = c1 + k1;
    x0 += x1; x1 = rotl32(x1, 13); x1 ^= x0;
    x0 += x1; x1 = rotl32(x1, 15); x1 ^= x0;
    x0 += x1; x1 = rotl32(x1, 26); x1 ^= x0;
    x0 += x1; x1 = rotl32(x1,  6); x1 ^= x0;
    x0 += k1;  x1 += ks2 + 1u;
    x0 += x1; x1 = rotl32(x1, 17); x1 ^= x0;
    x0 += x1; x1 = rotl32(x1, 29); x1 ^= x0;
    x0 += x1; x1 = rotl32(x1, 16); x1 ^= x0;
    x0 += x1; x1 = rotl32(x1, 24); x1 ^= x0;
    x0 += ks2; x1 += k0 + 2u;
    x0 += x1; x1 = rotl32(x1, 13); x1 ^= x0;
    x0 += x1; x1 = rotl32(x1, 15); x1 ^= x0;
    x0 += x1; x1 = rotl32(x1, 26); x1 ^= x0;
    x0 += x1; x1 = rotl32(x1,  6); x1 ^= x0;
    x0 += k0;  x1 += k1 + 3u;
    x0 += x1; x1 = rotl32(x1, 17); x1 ^= x0;
    x0 += x1; x1 = rotl32(x1, 29); x1 ^= x0;
    x0 += x1; x1 = rotl32(x1, 16); x1 ^= x0;
    x0 += x1; x1 = rotl32(x1, 24); x1 ^= x0;
    x0 += k1;  x1 += ks2 + 4u;
    x0 += x1; x1 = rotl32(x1, 13); x1 ^= x0;
    x0 += x1; x1 = rotl32(x1, 15); x1 ^= x0;
    x0 += x1; x1 = rotl32(x1, 26); x1 ^= x0;
    x0 += x1; x1 = rotl32(x1,  6); x1 ^= x0;
    x0 += ks2; x1 += k0 + 5u;
    o0 = x0; o1 = x1;
}

__device__ __forceinline__ uint32_t rbits32(uint32_t k0, uint32_t k1, uint32_t idx) {
    uint32_t o0, o1;
    threefry(k0, k1, 0u, idx, o0, o1);
    return o0 ^ o1;
}

__device__ __forceinline__ float u01_from_bits(uint32_t bits) {
    return __uint_as_float((bits >> 9) | 0x3f800000u) - 1.0f;
}

__device__ float erfinv_xla(float x) {
    #pragma clang fp contract(off)
    float w = -log1pf(-x * x);
    float p;
    if (w < 5.0f) {
        w = w - 2.5f;
        p = 2.81022636e-08f;
        p = 3.43273939e-07f + p * w;
        p = -3.5233877e-06f + p * w;
        p = -4.39150654e-06f + p * w;
        p = 0.00021858087f + p * w;
        p = -0.00125372503f + p * w;
        p = -0.00417768164f + p * w;
        p = 0.246640727f + p * w;
        p = 1.50140941f + p * w;
    } else {
        w = sqrtf(w) - 3.0f;
        p = -0.000200214257f;
        p = 0.000100950558f + p * w;
        p = 0.00134934322f + p * w;
        p = -0.00367342844f + p * w;
        p = 0.00573950773f + p * w;
        p = -0.0076224613f + p * w;
        p = 0.00943887047f + p * w;
        p = 1.00167406f + p * w;
        p = 2.83297682f + p * w;
    }
    return p * x;
}

// ---------------- workspace layout (float offsets) ----------------
#define P_OFF      0           // 8192*12
#define NK_OFF     98304       // 4 u32 (16 f reserved)
#define W2GT_OFF   98320       // 64*296 bf16 = 9472 f
#define WFB_OFF    107792      // 512*3136 bf16 = 802816 f
#define WP1B_OFF   910608      // 512*512 bf16 = 131072 f
#define WP2B_OFF   1041680     // 128*512 bf16 = 32768 f
#define DATA_OFF   1074448
// batched (padded AUG 30x30): AUG8P 8192*900 f32, PL28 8192*3136 bf16, H8 8192*512 bf16
#define BATCH_FLOATS 23389456ull   // = DATA_OFF + 7372800 + 12845056 + 2097152 (93.6 MB)
// per-view fallback: AUGP 4096*900, PL2 4096*3136 bf16, H 4096*512 bf16 (48.9 MB)

// ---------------- kernels ----------------
__global__ void param_kernel(float* __restrict__ P, uint32_t* __restrict__ NK) {
    #pragma clang fp contract(off)
    int gid = blockIdx.x * blockDim.x + threadIdx.x;
    if (gid >= 8192) return;
    int v = gid >> 12;
    int i = gid & 4095;

    uint32_t kv0, kv1;
    threefry(0u, 42u, 0u, (uint32_t)v, kv0, kv1);

    uint32_t sk0[11], sk1[11];
    #pragma unroll
    for (int j = 0; j < 11; ++j) threefry(kv0, kv1, 0u, (uint32_t)j, sk0[j], sk1[j]);

    float u[10];
    #pragma unroll
    for (int j = 0; j < 10; ++j) u[j] = u01_from_bits(rbits32(sk0[j], sk1[j], (uint32_t)i));

    float crop = floorf(28.0f * (0.7f + 0.3f * u[0]));
    float top  = floorf((28.0f - crop) * u[1]);
    float left = floorf((28.0f - crop) * u[2]);
    float flip = (u[3] < 0.5f) ? 1.0f : 0.0f;
    float rot  = (u[4] < 0.8f) ? 1.0f : 0.0f;
    float rad  = ((20.0f * u[5] - 10.0f) * 3.14159274101257324f) / 180.0f;
    float cj   = (u[6] < 0.8f) ? 1.0f : 0.0f;
    float bb   = 0.2f * u[7] - 0.1f;
    float cc   = 0.8f + 0.4f * u[8];
    float na   = (u[9] < 0.5f) ? 1.0f : 0.0f;

    float* p = P + gid * 12;
    p[0] = crop; p[1] = top; p[2] = left; p[3] = flip; p[4] = rot;
    p[5] = rad;  p[6] = cj;  p[7] = bb;   p[8] = cc;   p[9] = na;
    p[10] = cosf(rad); p[11] = sinf(rad);

    if (i == 0) { NK[v * 2] = sk0[10]; NK[v * 2 + 1] = sk1[10]; }
}

// W2 (64,32,3,3) -> W2gT[oc][k=(ky*3+kx)*32+ic], padded row stride 296, bf16
__global__ void wprep_w2(const float* __restrict__ W2, ushort* __restrict__ W2gT) {
    int idx = blockIdx.x * 256 + threadIdx.x;
    if (idx >= 64 * 296) return;
    int oc = idx / 296, k = idx % 296;
    float v = 0.0f;
    if (k < 288) {
        int s = k >> 5, ic = k & 31;
        int ky = s / 3, kx = s % 3;
        v = W2[((oc * 32 + ic) * 3 + ky) * 3 + kx];
    }
    W2gT[idx] = f2bf(v);
}

// Wf (512, 3136=oc*49+pos) -> WfB[n][k'=pos*64+oc] bf16
__global__ void wprep_wf(const float* __restrict__ Wf, ushort* __restrict__ WfB) {
    int idx = blockIdx.x * 256 + threadIdx.x;
    if (idx >= 512 * 3136) return;
    int n = idx / 3136, kp = idx % 3136;
    int pos = kp >> 6, oc = kp & 63;
    WfB[idx] = f2bf(Wf[n * 3136 + oc * 49 + pos]);
}

__global__ void wprep_cast(const float* __restrict__ src, ushort* __restrict__ dst, int n) {
    int idx = blockIdx.x * 256 + threadIdx.x;
    if (idx < n) dst[idx] = f2bf(src[idx]);
}

// Block-per-image augment -> PADDED 30x30 output (row stride 30, zero border).
// li = blockIdx.x; global image id r = base + li.
__global__ __launch_bounds__(256) void augment_kernel(const float* __restrict__ x,
                                                      const float* __restrict__ P,
                                                      const uint32_t* __restrict__ NK,
                                                      float* __restrict__ AUGP, int base) {
    #pragma clang fp contract(off)
    int li = blockIdx.x;
    int r = base + li;
    int v = r >> 12, i = r & 4095;
    int t = threadIdx.x;
    __shared__ float img[784];
    __shared__ float s1[784];
    __shared__ float srctab[28];

    const float* p = P + r * 12;
    float crop = p[0], top = p[1], left = p[2];
    int flip = (p[3] != 0.0f);
    int rot  = (p[4] != 0.0f);
    int cj = (p[6] != 0.0f);
    float bb = p[7], cc = p[8];
    int na = (p[9] != 0.0f);
    float cs = p[10], sn = p[11];
    uint32_t nk0 = NK[v * 2], nk1 = NK[v * 2 + 1];

    float* Ao = AUGP + (size_t)li * 900;
    // zero whole padded tile (interior is dead-store, overwritten after barriers;
    // __syncthreads drains vmcnt so ordering is guaranteed)
    for (int q = t; q < 900; q += 256) Ao[q] = 0.0f;

    for (int q = t; q < 784; q += 256) img[q] = x[i * 784 + q];
    if (t < 28) {
        float j = (float)t + 0.5f;
        float s = j * crop / 28.0f - 0.5f;
        srctab[t] = fminf(fmaxf(s, 0.0f), crop - 1.0f);
    }
    __syncthreads();

    for (int q = t; q < 784; q += 256) {
        int py = q / 28, px = q - (q / 28) * 28;
        int sxcol = flip ? (27 - px) : px;
        float yy = srctab[py] + top;
        float xx = srctab[sxcol] + left;
        float y0f = floorf(yy), x0f = floorf(xx);
        float wy = yy - y0f, wx = xx - x0f;
        int y0 = (int)y0f, x0 = (int)x0f;

        int yc0 = min(max(y0, 0), 27),     xc0 = min(max(x0, 0), 27);
        int yc1 = min(max(y0 + 1, 0), 27), xc1 = min(max(x0 + 1, 0), 27);
        float g00 = img[yc0 * 28 + xc0];
        float g01 = img[yc0 * 28 + xc1];
        float g10 = img[yc1 * 28 + xc0];
        float g11 = img[yc1 * 28 + xc1];
        float val = g00 * (1.0f - wy) * (1.0f - wx) + g01 * (1.0f - wy) * wx
                  + g10 * wy * (1.0f - wx) + g11 * wy * wx;
        s1[q] = val;
    }
    __syncthreads();

    for (int q = t; q < 784; q += 256) {
        int py = q / 28, px = q - (q / 28) * 28;
        float val;
        if (rot) {
            float Yn = (2.0f * (float)py + 1.0f) / 28.0f - 1.0f;
            float Xn = (2.0f * (float)px + 1.0f) / 28.0f - 1.0f;
            float xs = cs * Xn - sn * Yn;
            float ys = sn * Xn + cs * Yn;
            float ix = ((xs + 1.0f) * 28.0f - 1.0f) / 2.0f;
            float iy = ((ys + 1.0f) * 28.0f - 1.0f) / 2.0f;
            float y0f = floorf(iy), x0f = floorf(ix);
            float wy = iy - y0f, wx = ix - x0f;
            int y0 = (int)y0f, x0 = (int)x0f;
            float g[2][2];
            #pragma unroll
            for (int dy = 0; dy < 2; ++dy) {
                #pragma unroll
                for (int dx = 0; dx < 2; ++dx) {
                    int yi = y0 + dy, xi = x0 + dx;
                    int yc = min(max(yi, 0), 27), xc = min(max(xi, 0), 27);
                    float vv = s1[yc * 28 + xc];
                    float valid = (yi >= 0 && yi < 28 && xi >= 0 && xi < 28) ? 1.0f : 0.0f;
                    g[dy][dx] = vv * valid;
                }
            }
            val = g[0][0] * (1.0f - wy) * (1.0f - wx) + g[0][1] * (1.0f - wy) * wx
                + g[1][0] * wy * (1.0f - wx) + g[1][1] * wy * wx;
        } else {
            val = s1[q];
        }

        if (cj) {
            float vc = fminf(fmaxf(val + bb, 0.0f), 1.0f);
            val = fminf(fmaxf((vc - 0.5f) * cc + 0.5f, 0.0f), 1.0f);
        }

        if (na) {
            int idx = i * 784 + q;
            uint32_t bits = rbits32(nk0, nk1, (uint32_t)idx);
            float f = u01_from_bits(bits);
            const float lo = -0.99999994f;
            float uu = f * 2.0f + lo;
            uu = fmaxf(lo, uu);
            float n = 1.4142135623730951f * erfinv_xla(uu);
            val = fminf(fmaxf(val + 0.05f * n, 0.0f), 1.0f);
        }

        Ao[(py + 1) * 30 + (px + 1)] = (val - 0.5f) / 0.5f;
    }
}

// conv12: conv1 MFMA (padded im2col: NO bounds checks, float2 loads,
// XOR-swizzled A1) + conv2 MFMA (wave-per-oc-tile). A1/pl1p alias.
__global__ __launch_bounds__(256) void conv12_kernel(
        const float* __restrict__ AUGP,
        const float* __restrict__ W1, const float* __restrict__ b1,
        const ushort* __restrict__ W2gT, const float* __restrict__ b2,
        ushort* __restrict__ PL2) {
    int i = blockIdx.x, t = threadIdx.x;
    __shared__ __align__(16) ushort buf[12608];           // 1576 uint4 units
    __shared__ __align__(16) ushort w1sT[32 * 32];        // [oc][k]
    ushort* A1   = buf;
    ushort* pl1p = buf;

    {
        int q0 = t * 4;
        #pragma unroll
        for (int j = 0; j < 4; ++j) {
            int q = q0 + j;
            int oc = q >> 5, k = q & 31;
            w1sT[q] = (k < 9) ? f2bf(W1[oc * 9 + k]) : (ushort)0;
        }
    }

    const float* Ai = AUGP + (size_t)i * 900;
    if (t < 196) {
        int py = t / 14, px = t - (t / 14) * 14;
        int base = (2 * py) * 30 + 2 * px;   // padded coords, both even -> float2 aligned
        uint32_t u[4][4];
        #pragma unroll
        for (int ry = 0; ry < 4; ++ry) {
            float2 a = *(const float2*)(Ai + base + ry * 30);
            float2 b = *(const float2*)(Ai + base + ry * 30 + 2);
            u[ry][0] = (uint32_t)f2bf(a.x);
            u[ry][1] = (uint32_t)f2bf(a.y);
            u[ry][2] = (uint32_t)f2bf(b.x);
            u[ry][3] = (uint32_t)f2bf(b.y);
        }
        int tx = t & 7;
        #pragma unroll
        for (int w = 0; w < 4; ++w) {
            int dy = w >> 1, dx = w & 1;
            uint4 W0, W1v;
            W0.x = u[dy][dx]     | (u[dy][dx + 1] << 16);
            W0.y = u[dy][dx + 2] | (u[dy + 1][dx] << 16);
            W0.z = u[dy + 1][dx + 1] | (u[dy + 1][dx + 2] << 16);
            W0.w = u[dy + 2][dx]     | (u[dy + 2][dx + 1] << 16);
            W1v.x = u[dy + 2][dx + 2];
            W1v.y = 0; W1v.z = 0; W1v.w = 0;
            int u0 = t * 8 + w * 2;
            ((uint4*)A1)[u0 ^ tx]       = W0;
            ((uint4*)A1)[(u0 + 1) ^ tx] = W1v;
        }
    } else if (t < 204) {
        ((uint4*)A1)[1568 + (t - 196)] = uint4{0, 0, 0, 0};
    }
    __syncthreads();

    int l = t & 63, wv = t >> 6;
    int lr = l & 15, lg = l >> 4;

    float m0r[13], m1r[13];
    {
        bf16x8 bA = *(const bf16x8*)(w1sT + lr * 32 + lg * 8);
        bf16x8 bB = *(const bf16x8*)(w1sT + (16 + lr) * 32 + lg * 8);
        #pragma unroll
        for (int it = 0; it < 13; ++it) {
            int tt = wv + it * 4;
            if (tt < 49) {
                int u = (tt * 16 + lr) * 2 + lg;
                int su = u ^ ((u >> 3) & 7);
                bf16x8 af = *(const bf16x8*)(A1 + su * 8);
                f32x4 a0 = {0.0f, 0.0f, 0.0f, 0.0f};
                f32x4 a1acc = {0.0f, 0.0f, 0.0f, 0.0f};
                a0    = __builtin_amdgcn_mfma_f32_16x16x32_bf16(af, bA, a0, 0, 0, 0);
                a1acc = __builtin_amdgcn_mfma_f32_16x16x32_bf16(af, bB, a1acc, 0, 0, 0);
                m0r[it] = fmaxf(fmaxf(a0[0], a0[1]), fmaxf(a0[2], a0[3]));
                m1r[it] = fmaxf(fmaxf(a1acc[0], a1acc[1]), fmaxf(a1acc[2], a1acc[3]));
            }
        }
    }
    __syncthreads();

    for (int q = t; q < 1440; q += 256) ((uint4*)pl1p)[q] = uint4{0, 0, 0, 0};
    __syncthreads();

    {
        float bia0 = b1[lr], bia1 = b1[16 + lr];
        #pragma unroll
        for (int it = 0; it < 13; ++it) {
            int tt = wv + it * 4;
            if (tt < 49) {
                int pidx = tt * 4 + lg;
                int py = pidx / 14, px = pidx - py * 14;
                int base = ((py + 1) * 18 + (px + 1)) * 40;
                pl1p[base + lr]      = f2bf(fmaxf(m0r[it] + bia0, 0.0f));
                pl1p[base + 16 + lr] = f2bf(fmaxf(m1r[it] + bia1, 0.0f));
            }
        }
    }
    __syncthreads();

    {
        bf16x8 bfr[9];
        #pragma unroll
        for (int s = 0; s < 9; ++s)
            bfr[s] = *(const bf16x8*)(W2gT + (wv * 16 + lr) * 296 + s * 32 + lg * 8);
        float bias2 = b2[wv * 16 + lr];

        #pragma unroll
        for (int pyp = 0; pyp < 7; ++pyp) {
            int py0 = pyp * 2;
            bf16x8 f[4][3];
            #pragma unroll
            for (int j = 0; j < 4; ++j)
                #pragma unroll
                for (int kx = 0; kx < 3; ++kx)
                    f[j][kx] = *(const bf16x8*)(pl1p + ((py0 + j) * 18 + (lr + kx)) * 40 + lg * 8);
            f32x4 acc0 = {bias2, bias2, bias2, bias2};
            f32x4 acc1 = acc0;
            #pragma unroll
            for (int ky = 0; ky < 3; ++ky)
                #pragma unroll
                for (int kx = 0; kx < 3; ++kx) {
                    acc0 = __builtin_amdgcn_mfma_f32_16x16x32_bf16(f[ky][kx],     bfr[ky * 3 + kx], acc0, 0, 0, 0);
                    acc1 = __builtin_amdgcn_mfma_f32_16x16x32_bf16(f[ky + 1][kx], bfr[ky * 3 + kx], acc1, 0, 0, 0);
                }
            float v0 = fmaxf(fmaxf(fmaxf(acc0[0], acc0[1]), fmaxf(acc1[0], acc1[1])), 0.0f);
            float v1 = fmaxf(fmaxf(fmaxf(acc0[2], acc0[3]), fmaxf(acc1[2], acc1[3])), 0.0f);
            int px0 = lg * 2, px1 = px0 + 1;
            size_t base = (size_t)i * 3136 + (size_t)(pyp * 7) * 64 + wv * 16 + lr;
            PL2[base + (size_t)px0 * 64] = f2bf(v0);
            if (px1 < 7) PL2[base + (size_t)px1 * 64] = f2bf(v1);
        }
    }
}

// Generic bf16 GEMM: C[M][N] = A[M][K] * BT[N][K]^T + bias, 64x64 tile, BK=64,
// 4 waves (2x2), double-buffered swizzled LDS (proven).
template<bool RELU, bool OUT_BF16>
__global__ __launch_bounds__(256) void gemm_bt_kernel(
        const ushort* __restrict__ A, const ushort* __restrict__ BT,
        const float* __restrict__ bias, void* __restrict__ Cout,
        int M, int N, int K) {
    __shared__ __align__(16) ushort lds[2][2][4096];   // [buf][A/B][64*64] bf16
    int t = threadIdx.x;
    int w = t >> 6, l = t & 63;
    int lr = l & 15, lc = l >> 4;
    int wm = w >> 1, wn = w & 1;
    int bm = blockIdx.x, bn = blockIdx.y;
    int NKt = K >> 6;

    const ushort* Ab = A + (size_t)bm * 64 * K;
    const ushort* Bb = BT + (size_t)bn * 64 * K;

    int r0 = t >> 3, s0 = t & 7;
    int c1i = t + 256;
    int r1 = c1i >> 3, s1 = c1i & 7;
    int d0 = r0 * 8 + (s0 ^ (r0 & 7));
    int d1 = r1 * 8 + (s1 ^ (r1 & 7));

    f32x4 acc[2][2] = {};

    uint4 tA0, tA1, tB0, tB1;
    #define GLOAD(kt) do { \
        tA0 = *(const uint4*)(Ab + (size_t)r0 * K + (kt) * 64 + s0 * 8); \
        tA1 = *(const uint4*)(Ab + (size_t)r1 * K + (kt) * 64 + s1 * 8); \
        tB0 = *(const uint4*)(Bb + (size_t)r0 * K + (kt) * 64 + s0 * 8); \
        tB1 = *(const uint4*)(Bb + (size_t)r1 * K + (kt) * 64 + s1 * 8); } while (0)
    #define LWRITE(bufi) do { \
        ((uint4*)lds[bufi][0])[d0] = tA0; ((uint4*)lds[bufi][0])[d1] = tA1; \
        ((uint4*)lds[bufi][1])[d0] = tB0; ((uint4*)lds[bufi][1])[d1] = tB1; } while (0)

    GLOAD(0); LWRITE(0);
    int buf = 0;
    for (int kt = 0; kt < NKt; ++kt) {
        __syncthreads();
        if (kt + 1 < NKt) GLOAD(kt + 1);
        const ushort* Al = lds[buf][0];
        const ushort* Bl = lds[buf][1];
        #pragma unroll
        for (int ks = 0; ks < 2; ++ks) {
            bf16x8 af[2], bg[2];
            #pragma unroll
            for (int mt = 0; mt < 2; ++mt) {
                int row = wm * 32 + mt * 16 + lr;
                int unit = row * 8 + ((ks * 4 + lc) ^ (row & 7));
                af[mt] = *(const bf16x8*)(Al + unit * 8);
            }
            #pragma unroll
            for (int nt = 0; nt < 2; ++nt) {
                int row = wn * 32 + nt * 16 + lr;
                int unit = row * 8 + ((ks * 4 + lc) ^ (row & 7));
                bg[nt] = *(const bf16x8*)(Bl + unit * 8);
            }
            #pragma unroll
            for (int mt = 0; mt < 2; ++mt)
                #pragma unroll
                for (int nt = 0; nt < 2; ++nt)
                    acc[mt][nt] = __builtin_amdgcn_mfma_f32_16x16x32_bf16(af[mt], bg[nt], acc[mt][nt], 0, 0, 0);
        }
        if (kt + 1 < NKt) LWRITE(buf ^ 1);
        buf ^= 1;
    }

    #pragma unroll
    for (int nt = 0; nt < 2; ++nt) {
        int gcol = bn * 64 + wn * 32 + nt * 16 + lr;
        float bv = bias[gcol];
        #pragma unroll
        for (int mt = 0; mt < 2; ++mt) {
            #pragma unroll
            for (int rg = 0; rg < 4; ++rg) {
                int grow = bm * 64 + wm * 32 + mt * 16 + lc * 4 + rg;
                float vv = acc[mt][nt][rg] + bv;
                if (RELU) vv = fmaxf(vv, 0.0f);
                if (OUT_BF16) ((ushort*)Cout)[(size_t)grow * N + gcol] = f2bf(vv);
                else          ((float*)Cout)[(size_t)grow * N + gcol] = vv;
            }
        }
    }
    #undef GLOAD
    #undef LWRITE
}

// ---------------- launch ----------------
extern "C" void kernel_launch(void* const* d_in, const int* in_sizes, int n_in,
                              void* d_out, int out_size, void* d_ws, size_t ws_size,
                              hipStream_t stream) {
    const float* x   = (const float*)d_in[0];
    const float* W1  = (const float*)d_in[1];
    const float* b1  = (const float*)d_in[2];
    const float* W2  = (const float*)d_in[3];
    const float* b2  = (const float*)d_in[4];
    const float* Wf  = (const float*)d_in[5];
    const float* bf  = (const float*)d_in[6];
    const float* Wp1 = (const float*)d_in[7];
    const float* bp1 = (const float*)d_in[8];
    const float* Wp2 = (const float*)d_in[9];
    const float* bp2 = (const float*)d_in[10];

    float* ws     = (float*)d_ws;
    float* P      = ws + P_OFF;
    uint32_t* NK  = (uint32_t*)(ws + NK_OFF);
    ushort* W2gT  = (ushort*)(ws + W2GT_OFF);
    ushort* WfB   = (ushort*)(ws + WFB_OFF);
    ushort* Wp1B  = (ushort*)(ws + WP1B_OFF);
    ushort* Wp2B  = (ushort*)(ws + WP2B_OFF);
    float* out    = (float*)d_out;

    param_kernel<<<32, 256, 0, stream>>>(P, NK);
    wprep_w2<<<74, 256, 0, stream>>>(W2, W2gT);
    wprep_wf<<<6272, 256, 0, stream>>>(Wf, WfB);
    wprep_cast<<<1024, 256, 0, stream>>>(Wp1, Wp1B, 512 * 512);
    wprep_cast<<<256, 256, 0, stream>>>(Wp2, Wp2B, 128 * 512);

    if (ws_size >= BATCH_FLOATS * 4ull) {
        // -------- batched: both views, padded AUG ----------------------------
        float* AUG8P = ws + DATA_OFF;                        // 8192*900 f32
        ushort* PL28 = (ushort*)(ws + DATA_OFF + 7372800);   // 8192*3136 bf16
        ushort* H8   = (ushort*)(ws + DATA_OFF + 20217856);  // 8192*512 bf16
        ushort* P18  = (ushort*)AUG8P;                       // alias

        augment_kernel<<<8192, 256, 0, stream>>>(x, P, NK, AUG8P, 0);
        conv12_kernel<<<8192, 256, 0, stream>>>(AUG8P, W1, b1, W2gT, b2, PL28);
        gemm_bt_kernel<false, true><<<dim3(128, 8), 256, 0, stream>>>(
            PL28, WfB, bf, H8, 8192, 512, 3136);
        gemm_bt_kernel<true, true><<<dim3(128, 8), 256, 0, stream>>>(
            H8, Wp1B, bp1, P18, 8192, 512, 512);
        gemm_bt_kernel<false, false><<<dim3(128, 2), 256, 0, stream>>>(
            P18, Wp2B, bp2, out, 8192, 128, 512);
    } else {
        // -------- per-view fallback (padded AUG) -----------------------------
        float* AUGP = ws + DATA_OFF;                         // 4096*900 f32
        ushort* PL2 = (ushort*)(ws + DATA_OFF + 3686400);    // 4096*3136 bf16
        ushort* Hb  = (ushort*)(ws + DATA_OFF + 10108928);   // 4096*512 bf16
        ushort* P1  = (ushort*)AUGP;

        for (int v = 0; v < 2; ++v) {
            augment_kernel<<<4096, 256, 0, stream>>>(x, P, NK, AUGP, v * 4096);
            conv12_kernel<<<4096, 256, 0, stream>>>(AUGP, W1, b1, W2gT, b2, PL2);
            gemm_bt_kernel<false, true><<<dim3(64, 8), 256, 0, stream>>>(
                PL2, WfB, bf, Hb, 4096, 512, 3136);
            gemm_bt_kernel<true, true><<<dim3(64, 8), 256, 0, stream>>>(
                Hb, Wp1B, bp1, P1, 4096, 512, 512);
            gemm_bt_kernel<false, false><<<dim3(64, 2), 256, 0, stream>>>(
                P1, Wp2B, bp2, out + (size_t)v * 4096 * 128, 4096, 128, 512);
        }
    }
}

// Round 18
// 226.343 us; speedup vs baseline: 1.8137x; 1.0085x over previous
//
#include <hip/hip_runtime.h>
#include <stdint.h>
#include <math.h>

typedef __attribute__((ext_vector_type(8))) short bf16x8;
typedef __attribute__((ext_vector_type(4))) float f32x4;

__device__ __forceinline__ ushort f2bf(float f) {      // RTNE, finite inputs
    uint32_t u = __float_as_uint(f);
    u += 0x7fffu + ((u >> 16) & 1u);
    return (ushort)(u >> 16);
}

// ---------------- Threefry-2x32 (JAX-exact, partitionable mode) ----------------
__device__ __forceinline__ uint32_t rotl32(uint32_t v, int r) {
    return (v << r) | (v >> (32 - r));
}

__device__ __forceinline__ void threefry(uint32_t k0, uint32_t k1,
                                         uint32_t c0, uint32_t c1,
                                         uint32_t& o0, uint32_t& o1) {
    uint32_t ks2 = k0 ^ k1 ^ 0x1BD11BDAu;
    uint32_t x0 = c0 + k0, x1 = c1 + k1;
    x0 += x1; x1 = rotl32(x1, 13); x1 ^= x0;
    x0 += x1; x1 = rotl32(x1, 15); x1 ^= x0;
    x0 += x1; x1 = rotl32(x1, 26); x1 ^= x0;
    x0 += x1; x1 = rotl32(x1,  6); x1 ^= x0;
    x0 += k1;  x1 += ks2 + 1u;
    x0 += x1; x1 = rotl32(x1, 17); x1 ^= x0;
    x0 += x1; x1 = rotl32(x1, 29); x1 ^= x0;
    x0 += x1; x1 = rotl32(x1, 16); x1 ^= x0;
    x0 += x1; x1 = rotl32(x1, 24); x1 ^= x0;
    x0 += ks2; x1 += k0 + 2u;
    x0 += x1; x1 = rotl32(x1, 13); x1 ^= x0;
    x0 += x1; x1 = rotl32(x1, 15); x1 ^= x0;
    x0 += x1; x1 = rotl32(x1, 26); x1 ^= x0;
    x0 += x1; x1 = rotl32(x1,  6); x1 ^= x0;
    x0 += k0;  x1 += k1 + 3u;
    x0 += x1; x1 = rotl32(x1, 17); x1 ^= x0;
    x0 += x1; x1 = rotl32(x1, 29); x1 ^= x0;
    x0 += x1; x1 = rotl32(x1, 16); x1 ^= x0;
    x0 += x1; x1 = rotl32(x1, 24); x1 ^= x0;
    x0 += k1;  x1 += ks2 + 4u;
    x0 += x1; x1 = rotl32(x1, 13); x1 ^= x0;
    x0 += x1; x1 = rotl32(x1, 15); x1 ^= x0;
    x0 += x1; x1 = rotl32(x1, 26); x1 ^= x0;
    x0 += x1; x1 = rotl32(x1,  6); x1 ^= x0;
    x0 += ks2; x1 += k0 + 5u;
    o0 = x0; o1 = x1;
}

__device__ __forceinline__ uint32_t rbits32(uint32_t k0, uint32_t k1, uint32_t idx) {
    uint32_t o0, o1;
    threefry(k0, k1, 0u, idx, o0, o1);
    return o0 ^ o1;
}

__device__ __forceinline__ float u01_from_bits(uint32_t bits) {
    return __uint_as_float((bits >> 9) | 0x3f800000u) - 1.0f;
}

__device__ float erfinv_xla(float x) {
    #pragma clang fp contract(off)
    float w = -log1pf(-x * x);
    float p;
    if (w < 5.0f) {
        w = w - 2.5f;
        p = 2.81022636e-08f;
        p = 3.43273939e-07f + p * w;
        p = -3.5233877e-06f + p * w;
        p = -4.39150654e-06f + p * w;
        p = 0.00021858087f + p * w;
        p = -0.00125372503f + p * w;
        p = -0.00417768164f + p * w;
        p = 0.246640727f + p * w;
        p = 1.50140941f + p * w;
    } else {
        w = sqrtf(w) - 3.0f;
        p = -0.000200214257f;
        p = 0.000100950558f + p * w;
        p = 0.00134934322f + p * w;
        p = -0.00367342844f + p * w;
        p = 0.00573950773f + p * w;
        p = -0.0076224613f + p * w;
        p = 0.00943887047f + p * w;
        p = 1.00167406f + p * w;
        p = 2.83297682f + p * w;
    }
    return p * x;
}

// ---------------- workspace layout (float offsets) ----------------
#define P_OFF      0           // 8192*12
#define NK_OFF     98304       // 4 u32 (16 f reserved)
#define W2GT_OFF   98320       // 64*296 bf16 = 9472 f
#define WFB_OFF    107792      // 512*3136 bf16 = 802816 f
#define WP1B_OFF   910608      // 512*512 bf16 = 131072 f
#define WP2B_OFF   1041680     // 128*512 bf16 = 32768 f
#define DATA_OFF   1074448
// batched: AUGB8 8192*900 bf16 (3686400 f), PL28 8192*3136 bf16 (12845056 f),
//          H8 8192*512 bf16 (2097152 f) -> end 19,703,056 f = 78.8 MB
#define BATCH_FLOATS 19703056ull
// fallback per-view: AUGB 4096*900 bf16 (1843200 f), PL2 (6422528 f), H (1048576 f)
//          -> end 10,388,752 f = 41.6 MB

// ---------------- kernels ----------------
__global__ void param_kernel(float* __restrict__ P, uint32_t* __restrict__ NK) {
    #pragma clang fp contract(off)
    int gid = blockIdx.x * blockDim.x + threadIdx.x;
    if (gid >= 8192) return;
    int v = gid >> 12;
    int i = gid & 4095;

    uint32_t kv0, kv1;
    threefry(0u, 42u, 0u, (uint32_t)v, kv0, kv1);

    uint32_t sk0[11], sk1[11];
    #pragma unroll
    for (int j = 0; j < 11; ++j) threefry(kv0, kv1, 0u, (uint32_t)j, sk0[j], sk1[j]);

    float u[10];
    #pragma unroll
    for (int j = 0; j < 10; ++j) u[j] = u01_from_bits(rbits32(sk0[j], sk1[j], (uint32_t)i));

    float crop = floorf(28.0f * (0.7f + 0.3f * u[0]));
    float top  = floorf((28.0f - crop) * u[1]);
    float left = floorf((28.0f - crop) * u[2]);
    float flip = (u[3] < 0.5f) ? 1.0f : 0.0f;
    float rot  = (u[4] < 0.8f) ? 1.0f : 0.0f;
    float rad  = ((20.0f * u[5] - 10.0f) * 3.14159274101257324f) / 180.0f;
    float cj   = (u[6] < 0.8f) ? 1.0f : 0.0f;
    float bb   = 0.2f * u[7] - 0.1f;
    float cc   = 0.8f + 0.4f * u[8];
    float na   = (u[9] < 0.5f) ? 1.0f : 0.0f;

    float* p = P + gid * 12;
    p[0] = crop; p[1] = top; p[2] = left; p[3] = flip; p[4] = rot;
    p[5] = rad;  p[6] = cj;  p[7] = bb;   p[8] = cc;   p[9] = na;
    p[10] = cosf(rad); p[11] = sinf(rad);

    if (i == 0) { NK[v * 2] = sk0[10]; NK[v * 2 + 1] = sk1[10]; }
}

// W2 (64,32,3,3) -> W2gT[oc][k=(ky*3+kx)*32+ic], padded row stride 296, bf16
__global__ void wprep_w2(const float* __restrict__ W2, ushort* __restrict__ W2gT) {
    int idx = blockIdx.x * 256 + threadIdx.x;
    if (idx >= 64 * 296) return;
    int oc = idx / 296, k = idx % 296;
    float v = 0.0f;
    if (k < 288) {
        int s = k >> 5, ic = k & 31;
        int ky = s / 3, kx = s % 3;
        v = W2[((oc * 32 + ic) * 3 + ky) * 3 + kx];
    }
    W2gT[idx] = f2bf(v);
}

// Wf (512, 3136=oc*49+pos) -> WfB[n][k'=pos*64+oc] bf16
__global__ void wprep_wf(const float* __restrict__ Wf, ushort* __restrict__ WfB) {
    int idx = blockIdx.x * 256 + threadIdx.x;
    if (idx >= 512 * 3136) return;
    int n = idx / 3136, kp = idx % 3136;
    int pos = kp >> 6, oc = kp & 63;
    WfB[idx] = f2bf(Wf[n * 3136 + oc * 49 + pos]);
}

__global__ void wprep_cast(const float* __restrict__ src, ushort* __restrict__ dst, int n) {
    int idx = blockIdx.x * 256 + threadIdx.x;
    if (idx < n) dst[idx] = f2bf(src[idx]);
}

// Block-per-image augment -> PADDED 30x30 BF16 output (row stride 30, zero
// border). f2bf here is bit-identical to the one conv12 previously applied.
__global__ __launch_bounds__(256) void augment_kernel(const float* __restrict__ x,
                                                      const float* __restrict__ P,
                                                      const uint32_t* __restrict__ NK,
                                                      ushort* __restrict__ AUGB, int base) {
    #pragma clang fp contract(off)
    int li = blockIdx.x;
    int r = base + li;
    int v = r >> 12, i = r & 4095;
    int t = threadIdx.x;
    __shared__ float img[784];
    __shared__ float s1[784];
    __shared__ float srctab[28];

    const float* p = P + r * 12;
    float crop = p[0], top = p[1], left = p[2];
    int flip = (p[3] != 0.0f);
    int rot  = (p[4] != 0.0f);
    int cj = (p[6] != 0.0f);
    float bb = p[7], cc = p[8];
    int na = (p[9] != 0.0f);
    float cs = p[10], sn = p[11];
    uint32_t nk0 = NK[v * 2], nk1 = NK[v * 2 + 1];

    ushort* Ao = AUGB + (size_t)li * 900;
    // zero whole padded tile via u32 stores (450 words); interior re-written
    // after barriers (vmcnt drained by __syncthreads -> ordering guaranteed)
    for (int q = t; q < 450; q += 256) ((uint32_t*)Ao)[q] = 0u;

    for (int q = t; q < 784; q += 256) img[q] = x[i * 784 + q];
    if (t < 28) {
        float j = (float)t + 0.5f;
        float s = j * crop / 28.0f - 0.5f;
        srctab[t] = fminf(fmaxf(s, 0.0f), crop - 1.0f);
    }
    __syncthreads();

    for (int q = t; q < 784; q += 256) {
        int py = q / 28, px = q - (q / 28) * 28;
        int sxcol = flip ? (27 - px) : px;
        float yy = srctab[py] + top;
        float xx = srctab[sxcol] + left;
        float y0f = floorf(yy), x0f = floorf(xx);
        float wy = yy - y0f, wx = xx - x0f;
        int y0 = (int)y0f, x0 = (int)x0f;

        int yc0 = min(max(y0, 0), 27),     xc0 = min(max(x0, 0), 27);
        int yc1 = min(max(y0 + 1, 0), 27), xc1 = min(max(x0 + 1, 0), 27);
        float g00 = img[yc0 * 28 + xc0];
        float g01 = img[yc0 * 28 + xc1];
        float g10 = img[yc1 * 28 + xc0];
        float g11 = img[yc1 * 28 + xc1];
        float val = g00 * (1.0f - wy) * (1.0f - wx) + g01 * (1.0f - wy) * wx
                  + g10 * wy * (1.0f - wx) + g11 * wy * wx;
        s1[q] = val;
    }
    __syncthreads();

    for (int q = t; q < 784; q += 256) {
        int py = q / 28, px = q - (q / 28) * 28;
        float val;
        if (rot) {
            float Yn = (2.0f * (float)py + 1.0f) / 28.0f - 1.0f;
            float Xn = (2.0f * (float)px + 1.0f) / 28.0f - 1.0f;
            float xs = cs * Xn - sn * Yn;
            float ys = sn * Xn + cs * Yn;
            float ix = ((xs + 1.0f) * 28.0f - 1.0f) / 2.0f;
            float iy = ((ys + 1.0f) * 28.0f - 1.0f) / 2.0f;
            float y0f = floorf(iy), x0f = floorf(ix);
            float wy = iy - y0f, wx = ix - x0f;
            int y0 = (int)y0f, x0 = (int)x0f;
            float g[2][2];
            #pragma unroll
            for (int dy = 0; dy < 2; ++dy) {
                #pragma unroll
                for (int dx = 0; dx < 2; ++dx) {
                    int yi = y0 + dy, xi = x0 + dx;
                    int yc = min(max(yi, 0), 27), xc = min(max(xi, 0), 27);
                    float vv = s1[yc * 28 + xc];
                    float valid = (yi >= 0 && yi < 28 && xi >= 0 && xi < 28) ? 1.0f : 0.0f;
                    g[dy][dx] = vv * valid;
                }
            }
            val = g[0][0] * (1.0f - wy) * (1.0f - wx) + g[0][1] * (1.0f - wy) * wx
                + g[1][0] * wy * (1.0f - wx) + g[1][1] * wy * wx;
        } else {
            val = s1[q];
        }

        if (cj) {
            float vc = fminf(fmaxf(val + bb, 0.0f), 1.0f);
            val = fminf(fmaxf((vc - 0.5f) * cc + 0.5f, 0.0f), 1.0f);
        }

        if (na) {
            int idx = i * 784 + q;
            uint32_t bits = rbits32(nk0, nk1, (uint32_t)idx);
            float f = u01_from_bits(bits);
            const float lo = -0.99999994f;
            float uu = f * 2.0f + lo;
            uu = fmaxf(lo, uu);
            float n = 1.4142135623730951f * erfinv_xla(uu);
            val = fminf(fmaxf(val + 0.05f * n, 0.0f), 1.0f);
        }

        Ao[(py + 1) * 30 + (px + 1)] = f2bf((val - 0.5f) / 0.5f);
    }
}

// conv12: conv1 MFMA (bf16 padded im2col: u32-pair loads, pure bit repack,
// NO converts, XOR-swizzled A1) + conv2 MFMA (wave-per-oc-tile). A1/pl1p alias.
__global__ __launch_bounds__(256) void conv12_kernel(
        const ushort* __restrict__ AUGB,
        const float* __restrict__ W1, const float* __restrict__ b1,
        const ushort* __restrict__ W2gT, const float* __restrict__ b2,
        ushort* __restrict__ PL2) {
    int i = blockIdx.x, t = threadIdx.x;
    __shared__ __align__(16) ushort buf[12608];           // 1576 uint4 units
    __shared__ __align__(16) ushort w1sT[32 * 32];        // [oc][k]
    ushort* A1   = buf;
    ushort* pl1p = buf;

    {
        int q0 = t * 4;
        #pragma unroll
        for (int j = 0; j < 4; ++j) {
            int q = q0 + j;
            int oc = q >> 5, k = q & 31;
            w1sT[q] = (k < 9) ? f2bf(W1[oc * 9 + k]) : (ushort)0;
        }
    }

    const ushort* Ai = AUGB + (size_t)i * 900;
    if (t < 196) {
        int py = t / 14, px = t - (t / 14) * 14;
        int e0 = (2 * py) * 30 + 2 * px;     // even -> u32-aligned
        uint32_t L[4], H[4];
        #pragma unroll
        for (int ry = 0; ry < 4; ++ry) {
            L[ry] = *(const uint32_t*)(Ai + e0 + ry * 30);       // c0|c1<<16
            H[ry] = *(const uint32_t*)(Ai + e0 + ry * 30 + 2);   // c2|c3<<16
        }
        int tx = t & 7;
        #pragma unroll
        for (int w = 0; w < 4; ++w) {
            int dy = w >> 1, dx = w & 1;
            uint32_t r0L = L[dy],     r0H = H[dy];
            uint32_t r1L = L[dy + 1], r1H = H[dy + 1];
            uint32_t r2L = L[dy + 2], r2H = H[dy + 2];
            uint4 W0, W1v;
            if (dx == 0) {
                W0.x = r0L;
                W0.y = (r0H & 0xffffu) | (r1L << 16);
                W0.z = (r1L >> 16) | (r1H << 16);
                W0.w = r2L;
                W1v.x = r2H & 0xffffu;
            } else {
                W0.x = (r0L >> 16) | (r0H << 16);
                W0.y = (r0H >> 16) | (r1L & 0xffff0000u);
                W0.z = r1H;
                W0.w = (r2L >> 16) | (r2H << 16);
                W1v.x = r2H >> 16;
            }
            W1v.y = 0; W1v.z = 0; W1v.w = 0;
            int u0 = t * 8 + w * 2;
            ((uint4*)A1)[u0 ^ tx]       = W0;
            ((uint4*)A1)[(u0 + 1) ^ tx] = W1v;
        }
    } else if (t < 204) {
        ((uint4*)A1)[1568 + (t - 196)] = uint4{0, 0, 0, 0};
    }
    __syncthreads();

    int l = t & 63, wv = t >> 6;
    int lr = l & 15, lg = l >> 4;

    float m0r[13], m1r[13];
    {
        bf16x8 bA = *(const bf16x8*)(w1sT + lr * 32 + lg * 8);
        bf16x8 bB = *(const bf16x8*)(w1sT + (16 + lr) * 32 + lg * 8);
        #pragma unroll
        for (int it = 0; it < 13; ++it) {
            int tt = wv + it * 4;
            if (tt < 49) {
                int u = (tt * 16 + lr) * 2 + lg;
                int su = u ^ ((u >> 3) & 7);
                bf16x8 af = *(const bf16x8*)(A1 + su * 8);
                f32x4 a0 = {0.0f, 0.0f, 0.0f, 0.0f};
                f32x4 a1acc = {0.0f, 0.0f, 0.0f, 0.0f};
                a0    = __builtin_amdgcn_mfma_f32_16x16x32_bf16(af, bA, a0, 0, 0, 0);
                a1acc = __builtin_amdgcn_mfma_f32_16x16x32_bf16(af, bB, a1acc, 0, 0, 0);
                m0r[it] = fmaxf(fmaxf(a0[0], a0[1]), fmaxf(a0[2], a0[3]));
                m1r[it] = fmaxf(fmaxf(a1acc[0], a1acc[1]), fmaxf(a1acc[2], a1acc[3]));
            }
        }
    }
    __syncthreads();

    for (int q = t; q < 1440; q += 256) ((uint4*)pl1p)[q] = uint4{0, 0, 0, 0};
    __syncthreads();

    {
        float bia0 = b1[lr], bia1 = b1[16 + lr];
        #pragma unroll
        for (int it = 0; it < 13; ++it) {
            int tt = wv + it * 4;
            if (tt < 49) {
                int pidx = tt * 4 + lg;
                int py = pidx / 14, px = pidx - py * 14;
                int base = ((py + 1) * 18 + (px + 1)) * 40;
                pl1p[base + lr]      = f2bf(fmaxf(m0r[it] + bia0, 0.0f));
                pl1p[base + 16 + lr] = f2bf(fmaxf(m1r[it] + bia1, 0.0f));
            }
        }
    }
    __syncthreads();

    {
        bf16x8 bfr[9];
        #pragma unroll
        for (int s = 0; s < 9; ++s)
            bfr[s] = *(const bf16x8*)(W2gT + (wv * 16 + lr) * 296 + s * 32 + lg * 8);
        float bias2 = b2[wv * 16 + lr];

        #pragma unroll
        for (int pyp = 0; pyp < 7; ++pyp) {
            int py0 = pyp * 2;
            bf16x8 f[4][3];
            #pragma unroll
            for (int j = 0; j < 4; ++j)
                #pragma unroll
                for (int kx = 0; kx < 3; ++kx)
                    f[j][kx] = *(const bf16x8*)(pl1p + ((py0 + j) * 18 + (lr + kx)) * 40 + lg * 8);
            f32x4 acc0 = {bias2, bias2, bias2, bias2};
            f32x4 acc1 = acc0;
            #pragma unroll
            for (int ky = 0; ky < 3; ++ky)
                #pragma unroll
                for (int kx = 0; kx < 3; ++kx) {
                    acc0 = __builtin_amdgcn_mfma_f32_16x16x32_bf16(f[ky][kx],     bfr[ky * 3 + kx], acc0, 0, 0, 0);
                    acc1 = __builtin_amdgcn_mfma_f32_16x16x32_bf16(f[ky + 1][kx], bfr[ky * 3 + kx], acc1, 0, 0, 0);
                }
            float v0 = fmaxf(fmaxf(fmaxf(acc0[0], acc0[1]), fmaxf(acc1[0], acc1[1])), 0.0f);
            float v1 = fmaxf(fmaxf(fmaxf(acc0[2], acc0[3]), fmaxf(acc1[2], acc1[3])), 0.0f);
            int px0 = lg * 2, px1 = px0 + 1;
            size_t base = (size_t)i * 3136 + (size_t)(pyp * 7) * 64 + wv * 16 + lr;
            PL2[base + (size_t)px0 * 64] = f2bf(v0);
            if (px1 < 7) PL2[base + (size_t)px1 * 64] = f2bf(v1);
        }
    }
}

// Generic bf16 GEMM: C[M][N] = A[M][K] * BT[N][K]^T + bias, 64x64 tile, BK=64,
// 4 waves (2x2), double-buffered swizzled LDS (proven).
template<bool RELU, bool OUT_BF16>
__global__ __launch_bounds__(256) void gemm_bt_kernel(
        const ushort* __restrict__ A, const ushort* __restrict__ BT,
        const float* __restrict__ bias, void* __restrict__ Cout,
        int M, int N, int K) {
    __shared__ __align__(16) ushort lds[2][2][4096];   // [buf][A/B][64*64] bf16
    int t = threadIdx.x;
    int w = t >> 6, l = t & 63;
    int lr = l & 15, lc = l >> 4;
    int wm = w >> 1, wn = w & 1;
    int bm = blockIdx.x, bn = blockIdx.y;
    int NKt = K >> 6;

    const ushort* Ab = A + (size_t)bm * 64 * K;
    const ushort* Bb = BT + (size_t)bn * 64 * K;

    int r0 = t >> 3, s0 = t & 7;
    int c1i = t + 256;
    int r1 = c1i >> 3, s1 = c1i & 7;
    int d0 = r0 * 8 + (s0 ^ (r0 & 7));
    int d1 = r1 * 8 + (s1 ^ (r1 & 7));

    f32x4 acc[2][2] = {};

    uint4 tA0, tA1, tB0, tB1;
    #define GLOAD(kt) do { \
        tA0 = *(const uint4*)(Ab + (size_t)r0 * K + (kt) * 64 + s0 * 8); \
        tA1 = *(const uint4*)(Ab + (size_t)r1 * K + (kt) * 64 + s1 * 8); \
        tB0 = *(const uint4*)(Bb + (size_t)r0 * K + (kt) * 64 + s0 * 8); \
        tB1 = *(const uint4*)(Bb + (size_t)r1 * K + (kt) * 64 + s1 * 8); } while (0)
    #define LWRITE(bufi) do { \
        ((uint4*)lds[bufi][0])[d0] = tA0; ((uint4*)lds[bufi][0])[d1] = tA1; \
        ((uint4*)lds[bufi][1])[d0] = tB0; ((uint4*)lds[bufi][1])[d1] = tB1; } while (0)

    GLOAD(0); LWRITE(0);
    int buf = 0;
    for (int kt = 0; kt < NKt; ++kt) {
        __syncthreads();
        if (kt + 1 < NKt) GLOAD(kt + 1);
        const ushort* Al = lds[buf][0];
        const ushort* Bl = lds[buf][1];
        #pragma unroll
        for (int ks = 0; ks < 2; ++ks) {
            bf16x8 af[2], bg[2];
            #pragma unroll
            for (int mt = 0; mt < 2; ++mt) {
                int row = wm * 32 + mt * 16 + lr;
                int unit = row * 8 + ((ks * 4 + lc) ^ (row & 7));
                af[mt] = *(const bf16x8*)(Al + unit * 8);
            }
            #pragma unroll
            for (int nt = 0; nt < 2; ++nt) {
                int row = wn * 32 + nt * 16 + lr;
                int unit = row * 8 + ((ks * 4 + lc) ^ (row & 7));
                bg[nt] = *(const bf16x8*)(Bl + unit * 8);
            }
            #pragma unroll
            for (int mt = 0; mt < 2; ++mt)
                #pragma unroll
                for (int nt = 0; nt < 2; ++nt)
                    acc[mt][nt] = __builtin_amdgcn_mfma_f32_16x16x32_bf16(af[mt], bg[nt], acc[mt][nt], 0, 0, 0);
        }
        if (kt + 1 < NKt) LWRITE(buf ^ 1);
        buf ^= 1;
    }

    #pragma unroll
    for (int nt = 0; nt < 2; ++nt) {
        int gcol = bn * 64 + wn * 32 + nt * 16 + lr;
        float bv = bias[gcol];
        #pragma unroll
        for (int mt = 0; mt < 2; ++mt) {
            #pragma unroll
            for (int rg = 0; rg < 4; ++rg) {
                int grow = bm * 64 + wm * 32 + mt * 16 + lc * 4 + rg;
                float vv = acc[mt][nt][rg] + bv;
                if (RELU) vv = fmaxf(vv, 0.0f);
                if (OUT_BF16) ((ushort*)Cout)[(size_t)grow * N + gcol] = f2bf(vv);
                else          ((float*)Cout)[(size_t)grow * N + gcol] = vv;
            }
        }
    }
    #undef GLOAD
    #undef LWRITE
}

// ---------------- launch ----------------
extern "C" void kernel_launch(void* const* d_in, const int* in_sizes, int n_in,
                              void* d_out, int out_size, void* d_ws, size_t ws_size,
                              hipStream_t stream) {
    const float* x   = (const float*)d_in[0];
    const float* W1  = (const float*)d_in[1];
    const float* b1  = (const float*)d_in[2];
    const float* W2  = (const float*)d_in[3];
    const float* b2  = (const float*)d_in[4];
    const float* Wf  = (const float*)d_in[5];
    const float* bf  = (const float*)d_in[6];
    const float* Wp1 = (const float*)d_in[7];
    const float* bp1 = (const float*)d_in[8];
    const float* Wp2 = (const float*)d_in[9];
    const float* bp2 = (const float*)d_in[10];

    float* ws     = (float*)d_ws;
    float* P      = ws + P_OFF;
    uint32_t* NK  = (uint32_t*)(ws + NK_OFF);
    ushort* W2gT  = (ushort*)(ws + W2GT_OFF);
    ushort* WfB   = (ushort*)(ws + WFB_OFF);
    ushort* Wp1B  = (ushort*)(ws + WP1B_OFF);
    ushort* Wp2B  = (ushort*)(ws + WP2B_OFF);
    float* out    = (float*)d_out;

    param_kernel<<<32, 256, 0, stream>>>(P, NK);
    wprep_w2<<<74, 256, 0, stream>>>(W2, W2gT);
    wprep_wf<<<6272, 256, 0, stream>>>(Wf, WfB);
    wprep_cast<<<1024, 256, 0, stream>>>(Wp1, Wp1B, 512 * 512);
    wprep_cast<<<256, 256, 0, stream>>>(Wp2, Wp2B, 128 * 512);

    if (ws_size >= BATCH_FLOATS * 4ull) {
        // -------- batched: both views, padded bf16 AUG -----------------------
        ushort* AUGB8 = (ushort*)(ws + DATA_OFF);            // 8192*900 bf16
        ushort* PL28  = (ushort*)(ws + DATA_OFF + 3686400);  // 8192*3136 bf16
        ushort* H8    = (ushort*)(ws + DATA_OFF + 16531456); // 8192*512 bf16
        ushort* P18   = AUGB8;                               // alias

        augment_kernel<<<8192, 256, 0, stream>>>(x, P, NK, AUGB8, 0);
        conv12_kernel<<<8192, 256, 0, stream>>>(AUGB8, W1, b1, W2gT, b2, PL28);
        gemm_bt_kernel<false, true><<<dim3(128, 8), 256, 0, stream>>>(
            PL28, WfB, bf, H8, 8192, 512, 3136);
        gemm_bt_kernel<true, true><<<dim3(128, 8), 256, 0, stream>>>(
            H8, Wp1B, bp1, P18, 8192, 512, 512);
        gemm_bt_kernel<false, false><<<dim3(128, 2), 256, 0, stream>>>(
            P18, Wp2B, bp2, out, 8192, 128, 512);
    } else {
        // -------- per-view fallback (padded bf16 AUG) ------------------------
        ushort* AUGB = (ushort*)(ws + DATA_OFF);             // 4096*900 bf16
        ushort* PL2  = (ushort*)(ws + DATA_OFF + 1843200);   // 4096*3136 bf16
        ushort* Hb   = (ushort*)(ws + DATA_OFF + 8265728);   // 4096*512 bf16
        ushort* P1   = AUGB;

        for (int v = 0; v < 2; ++v) {
            augment_kernel<<<4096, 256, 0, stream>>>(x, P, NK, AUGB, v * 4096);
            conv12_kernel<<<4096, 256, 0, stream>>>(AUGB, W1, b1, W2gT, b2, PL2);
            gemm_bt_kernel<false, true><<<dim3(64, 8), 256, 0, stream>>>(
                PL2, WfB, bf, Hb, 4096, 512, 3136);
            gemm_bt_kernel<true, true><<<dim3(64, 8), 256, 0, stream>>>(
                Hb, Wp1B, bp1, P1, 4096, 512, 512);
            gemm_bt_kernel<false, false><<<dim3(64, 2), 256, 0, stream>>>(
                P1, Wp2B, bp2, out + (size_t)v * 4096 * 128, 4096, 128, 512);
        }
    }
}

// Round 19
// 216.371 us; speedup vs baseline: 1.8973x; 1.0461x over previous
//
#include <hip/hip_runtime.h>
#include <stdint.h>
#include <math.h>

typedef __attribute__((ext_vector_type(8))) short bf16x8;
typedef __attribute__((ext_vector_type(4))) float f32x4;

__device__ __forceinline__ ushort f2bf(float f) {      // RTNE, finite inputs
    uint32_t u = __float_as_uint(f);
    u += 0x7fffu + ((u >> 16) & 1u);
    return (ushort)(u >> 16);
}

// ---------------- Threefry-2x32 (JAX-exact, partitionable mode) ----------------
__device__ __forceinline__ uint32_t rotl32(uint32_t v, int r) {
    return (v << r) | (v >> (32 - r));
}

__device__ __forceinline__ void threefry(uint32_t k0, uint32_t k1,
                                         uint32_t c0, uint32_t c1,
                                         uint32_t& o0, uint32_t& o1) {
    uint32_t ks2 = k0 ^ k1 ^ 0x1BD11BDAu;
    uint32_t x0 = c0 + k0, x1 = c1 + k1;
    x0 += x1; x1 = rotl32(x1, 13); x1 ^= x0;
    x0 += x1; x1 = rotl32(x1, 15); x1 ^= x0;
    x0 += x1; x1 = rotl32(x1, 26); x1 ^= x0;
    x0 += x1; x1 = rotl32(x1,  6); x1 ^= x0;
    x0 += k1;  x1 += ks2 + 1u;
    x0 += x1; x1 = rotl32(x1, 17); x1 ^= x0;
    x0 += x1; x1 = rotl32(x1, 29); x1 ^= x0;
    x0 += x1; x1 = rotl32(x1, 16); x1 ^= x0;
    x0 += x1; x1 = rotl32(x1, 24); x1 ^= x0;
    x0 += ks2; x1 += k0 + 2u;
    x0 += x1; x1 = rotl32(x1, 13); x1 ^= x0;
    x0 += x1; x1 = rotl32(x1, 15); x1 ^= x0;
    x0 += x1; x1 = rotl32(x1, 26); x1 ^= x0;
    x0 += x1; x1 = rotl32(x1,  6); x1 ^= x0;
    x0 += k0;  x1 += k1 + 3u;
    x0 += x1; x1 = rotl32(x1, 17); x1 ^= x0;
    x0 += x1; x1 = rotl32(x1, 29); x1 ^= x0;
    x0 += x1; x1 = rotl32(x1, 16); x1 ^= x0;
    x0 += x1; x1 = rotl32(x1, 24); x1 ^= x0;
    x0 += k1;  x1 += ks2 + 4u;
    x0 += x1; x1 = rotl32(x1, 13); x1 ^= x0;
    x0 += x1; x1 = rotl32(x1, 15); x1 ^= x0;
    x0 += x1; x1 = rotl32(x1, 26); x1 ^= x0;
    x0 += x1; x1 = rotl32(x1,  6); x1 ^= x0;
    x0 += ks2; x1 += k0 + 5u;
    o0 = x0; o1 = x1;
}

__device__ __forceinline__ uint32_t rbits32(uint32_t k0, uint32_t k1, uint32_t idx) {
    uint32_t o0, o1;
    threefry(k0, k1, 0u, idx, o0, o1);
    return o0 ^ o1;
}

__device__ __forceinline__ float u01_from_bits(uint32_t bits) {
    return __uint_as_float((bits >> 9) | 0x3f800000u) - 1.0f;
}

__device__ float erfinv_xla(float x) {
    #pragma clang fp contract(off)
    float w = -log1pf(-x * x);
    float p;
    if (w < 5.0f) {
        w = w - 2.5f;
        p = 2.81022636e-08f;
        p = 3.43273939e-07f + p * w;
        p = -3.5233877e-06f + p * w;
        p = -4.39150654e-06f + p * w;
        p = 0.00021858087f + p * w;
        p = -0.00125372503f + p * w;
        p = -0.00417768164f + p * w;
        p = 0.246640727f + p * w;
        p = 1.50140941f + p * w;
    } else {
        w = sqrtf(w) - 3.0f;
        p = -0.000200214257f;
        p = 0.000100950558f + p * w;
        p = 0.00134934322f + p * w;
        p = -0.00367342844f + p * w;
        p = 0.00573950773f + p * w;
        p = -0.0076224613f + p * w;
        p = 0.00943887047f + p * w;
        p = 1.00167406f + p * w;
        p = 2.83297682f + p * w;
    }
    return p * x;
}

// ---------------- workspace layout (float offsets) ----------------
#define P_OFF      0           // 8192*12
#define NK_OFF     98304       // 4 u32 (16 f reserved)
#define W2GT_OFF   98320       // 64*296 bf16 = 9472 f
#define WFB_OFF    107792      // 512*3136 bf16 = 802816 f
#define WP1B_OFF   910608      // 512*512 bf16 = 131072 f
#define WP2B_OFF   1041680     // 128*512 bf16 = 32768 f
#define DATA_OFF   1074448
// batched: AUGB8 8192*900 bf16 (3686400 f), PL28 8192*3136 bf16 (12845056 f),
//          H8 8192*512 bf16 (2097152 f) -> end 19,703,056 f = 78.8 MB
#define BATCH_FLOATS 19703056ull

// ---------------- merged prep kernel (param + all weight preps) ----------------
// block ranges: [0,32) param | [32,106) w2 | [106,6378) wf | [6378,7402) wp1 |
// [7402,7658) wp2
__global__ void prep_kernel(float* __restrict__ P, uint32_t* __restrict__ NK,
                            const float* __restrict__ W2, ushort* __restrict__ W2gT,
                            const float* __restrict__ Wf, ushort* __restrict__ WfB,
                            const float* __restrict__ Wp1, ushort* __restrict__ Wp1B,
                            const float* __restrict__ Wp2, ushort* __restrict__ Wp2B) {
    int b = blockIdx.x, t = threadIdx.x;
    if (b < 32) {
        #pragma clang fp contract(off)
        int gid = b * 256 + t;
        int v = gid >> 12;
        int i = gid & 4095;

        uint32_t kv0, kv1;
        threefry(0u, 42u, 0u, (uint32_t)v, kv0, kv1);

        uint32_t sk0[11], sk1[11];
        #pragma unroll
        for (int j = 0; j < 11; ++j) threefry(kv0, kv1, 0u, (uint32_t)j, sk0[j], sk1[j]);

        float u[10];
        #pragma unroll
        for (int j = 0; j < 10; ++j) u[j] = u01_from_bits(rbits32(sk0[j], sk1[j], (uint32_t)i));

        float crop = floorf(28.0f * (0.7f + 0.3f * u[0]));
        float top  = floorf((28.0f - crop) * u[1]);
        float left = floorf((28.0f - crop) * u[2]);
        float flip = (u[3] < 0.5f) ? 1.0f : 0.0f;
        float rot  = (u[4] < 0.8f) ? 1.0f : 0.0f;
        float rad  = ((20.0f * u[5] - 10.0f) * 3.14159274101257324f) / 180.0f;
        float cj   = (u[6] < 0.8f) ? 1.0f : 0.0f;
        float bb   = 0.2f * u[7] - 0.1f;
        float cc   = 0.8f + 0.4f * u[8];
        float na   = (u[9] < 0.5f) ? 1.0f : 0.0f;

        float* p = P + gid * 12;
        p[0] = crop; p[1] = top; p[2] = left; p[3] = flip; p[4] = rot;
        p[5] = rad;  p[6] = cj;  p[7] = bb;   p[8] = cc;   p[9] = na;
        p[10] = cosf(rad); p[11] = sinf(rad);

        if (i == 0) { NK[v * 2] = sk0[10]; NK[v * 2 + 1] = sk1[10]; }
    } else if (b < 106) {
        int idx = (b - 32) * 256 + t;
        if (idx < 64 * 296) {
            int oc = idx / 296, k = idx % 296;
            float v = 0.0f;
            if (k < 288) {
                int s = k >> 5, ic = k & 31;
                int ky = s / 3, kx = s % 3;
                v = W2[((oc * 32 + ic) * 3 + ky) * 3 + kx];
            }
            W2gT[idx] = f2bf(v);
        }
    } else if (b < 6378) {
        int idx = (b - 106) * 256 + t;
        if (idx < 512 * 3136) {
            int n = idx / 3136, kp = idx % 3136;
            int pos = kp >> 6, oc = kp & 63;
            WfB[idx] = f2bf(Wf[n * 3136 + oc * 49 + pos]);
        }
    } else if (b < 7402) {
        int idx = (b - 6378) * 256 + t;
        if (idx < 512 * 512) Wp1B[idx] = f2bf(Wp1[idx]);
    } else {
        int idx = (b - 7402) * 256 + t;
        if (idx < 128 * 512) Wp2B[idx] = f2bf(Wp2[idx]);
    }
}

// Block-per-image augment -> PADDED 30x30 BF16 output (row stride 30, zero border)
__global__ __launch_bounds__(256) void augment_kernel(const float* __restrict__ x,
                                                      const float* __restrict__ P,
                                                      const uint32_t* __restrict__ NK,
                                                      ushort* __restrict__ AUGB, int base) {
    #pragma clang fp contract(off)
    int li = blockIdx.x;
    int r = base + li;
    int v = r >> 12, i = r & 4095;
    int t = threadIdx.x;
    __shared__ float img[784];
    __shared__ float s1[784];
    __shared__ float srctab[28];

    const float* p = P + r * 12;
    float crop = p[0], top = p[1], left = p[2];
    int flip = (p[3] != 0.0f);
    int rot  = (p[4] != 0.0f);
    int cj = (p[6] != 0.0f);
    float bb = p[7], cc = p[8];
    int na = (p[9] != 0.0f);
    float cs = p[10], sn = p[11];
    uint32_t nk0 = NK[v * 2], nk1 = NK[v * 2 + 1];

    ushort* Ao = AUGB + (size_t)li * 900;
    for (int q = t; q < 450; q += 256) ((uint32_t*)Ao)[q] = 0u;

    for (int q = t; q < 784; q += 256) img[q] = x[i * 784 + q];
    if (t < 28) {
        float j = (float)t + 0.5f;
        float s = j * crop / 28.0f - 0.5f;
        srctab[t] = fminf(fmaxf(s, 0.0f), crop - 1.0f);
    }
    __syncthreads();

    for (int q = t; q < 784; q += 256) {
        int py = q / 28, px = q - (q / 28) * 28;
        int sxcol = flip ? (27 - px) : px;
        float yy = srctab[py] + top;
        float xx = srctab[sxcol] + left;
        float y0f = floorf(yy), x0f = floorf(xx);
        float wy = yy - y0f, wx = xx - x0f;
        int y0 = (int)y0f, x0 = (int)x0f;

        int yc0 = min(max(y0, 0), 27),     xc0 = min(max(x0, 0), 27);
        int yc1 = min(max(y0 + 1, 0), 27), xc1 = min(max(x0 + 1, 0), 27);
        float g00 = img[yc0 * 28 + xc0];
        float g01 = img[yc0 * 28 + xc1];
        float g10 = img[yc1 * 28 + xc0];
        float g11 = img[yc1 * 28 + xc1];
        float val = g00 * (1.0f - wy) * (1.0f - wx) + g01 * (1.0f - wy) * wx
                  + g10 * wy * (1.0f - wx) + g11 * wy * wx;
        s1[q] = val;
    }
    __syncthreads();

    for (int q = t; q < 784; q += 256) {
        int py = q / 28, px = q - (q / 28) * 28;
        float val;
        if (rot) {
            float Yn = (2.0f * (float)py + 1.0f) / 28.0f - 1.0f;
            float Xn = (2.0f * (float)px + 1.0f) / 28.0f - 1.0f;
            float xs = cs * Xn - sn * Yn;
            float ys = sn * Xn + cs * Yn;
            float ix = ((xs + 1.0f) * 28.0f - 1.0f) / 2.0f;
            float iy = ((ys + 1.0f) * 28.0f - 1.0f) / 2.0f;
            float y0f = floorf(iy), x0f = floorf(ix);
            float wy = iy - y0f, wx = ix - x0f;
            int y0 = (int)y0f, x0 = (int)x0f;
            float g[2][2];
            #pragma unroll
            for (int dy = 0; dy < 2; ++dy) {
                #pragma unroll
                for (int dx = 0; dx < 2; ++dx) {
                    int yi = y0 + dy, xi = x0 + dx;
                    int yc = min(max(yi, 0), 27), xc = min(max(xi, 0), 27);
                    float vv = s1[yc * 28 + xc];
                    float valid = (yi >= 0 && yi < 28 && xi >= 0 && xi < 28) ? 1.0f : 0.0f;
                    g[dy][dx] = vv * valid;
                }
            }
            val = g[0][0] * (1.0f - wy) * (1.0f - wx) + g[0][1] * (1.0f - wy) * wx
                + g[1][0] * wy * (1.0f - wx) + g[1][1] * wy * wx;
        } else {
            val = s1[q];
        }

        if (cj) {
            float vc = fminf(fmaxf(val + bb, 0.0f), 1.0f);
            val = fminf(fmaxf((vc - 0.5f) * cc + 0.5f, 0.0f), 1.0f);
        }

        if (na) {
            int idx = i * 784 + q;
            uint32_t bits = rbits32(nk0, nk1, (uint32_t)idx);
            float f = u01_from_bits(bits);
            const float lo = -0.99999994f;
            float uu = f * 2.0f + lo;
            uu = fmaxf(lo, uu);
            float n = 1.4142135623730951f * erfinv_xla(uu);
            val = fminf(fmaxf(val + 0.05f * n, 0.0f), 1.0f);
        }

        Ao[(py + 1) * 30 + (px + 1)] = f2bf((val - 0.5f) / 0.5f);
    }
}

// conv12: conv1 MFMA (bf16 padded im2col, XOR-swizzled A1) + conv2 MFMA
// (wave-per-oc-tile). A1/pl1p alias; scatter bases precomputed in ptbl.
__global__ __launch_bounds__(256) void conv12_kernel(
        const ushort* __restrict__ AUGB,
        const float* __restrict__ W1, const float* __restrict__ b1,
        const ushort* __restrict__ W2gT, const float* __restrict__ b2,
        ushort* __restrict__ PL2) {
    int i = blockIdx.x, t = threadIdx.x;
    __shared__ __align__(16) ushort buf[12608];           // 1576 uint4 units
    __shared__ __align__(16) ushort w1sT[32 * 32];        // [oc][k]
    __shared__ ushort ptbl[196];                          // scatter bases
    ushort* A1   = buf;
    ushort* pl1p = buf;

    {
        int q0 = t * 4;
        #pragma unroll
        for (int j = 0; j < 4; ++j) {
            int q = q0 + j;
            int oc = q >> 5, k = q & 31;
            w1sT[q] = (k < 9) ? f2bf(W1[oc * 9 + k]) : (ushort)0;
        }
    }

    const ushort* Ai = AUGB + (size_t)i * 900;
    if (t < 196) {
        int py = t / 14, px = t - (t / 14) * 14;
        int e0 = (2 * py) * 30 + 2 * px;     // even -> u32-aligned
        uint32_t L[4], H[4];
        #pragma unroll
        for (int ry = 0; ry < 4; ++ry) {
            L[ry] = *(const uint32_t*)(Ai + e0 + ry * 30);       // c0|c1<<16
            H[ry] = *(const uint32_t*)(Ai + e0 + ry * 30 + 2);   // c2|c3<<16
        }
        int tx = t & 7;
        #pragma unroll
        for (int w = 0; w < 4; ++w) {
            int dy = w >> 1, dx = w & 1;
            uint32_t r0L = L[dy],     r0H = H[dy];
            uint32_t r1L = L[dy + 1], r1H = H[dy + 1];
            uint32_t r2L = L[dy + 2], r2H = H[dy + 2];
            uint4 W0, W1v;
            if (dx == 0) {
                W0.x = r0L;
                W0.y = (r0H & 0xffffu) | (r1L << 16);
                W0.z = (r1L >> 16) | (r1H << 16);
                W0.w = r2L;
                W1v.x = r2H & 0xffffu;
            } else {
                W0.x = (r0L >> 16) | (r0H << 16);
                W0.y = (r0H >> 16) | (r1L & 0xffff0000u);
                W0.z = r1H;
                W0.w = (r2L >> 16) | (r2H << 16);
                W1v.x = r2H >> 16;
            }
            W1v.y = 0; W1v.z = 0; W1v.w = 0;
            int u0 = t * 8 + w * 2;
            ((uint4*)A1)[u0 ^ tx]       = W0;
            ((uint4*)A1)[(u0 + 1) ^ tx] = W1v;
        }
    } else if (t < 204) {
        ((uint4*)A1)[1568 + (t - 196)] = uint4{0, 0, 0, 0};
    } else {
        for (int e = t - 204; e < 196; e += 52) {
            int py = e / 14, px = e - (e / 14) * 14;
            ptbl[e] = (ushort)(((py + 1) * 18 + (px + 1)) * 40);
        }
    }
    __syncthreads();

    int l = t & 63, wv = t >> 6;
    int lr = l & 15, lg = l >> 4;

    float m0r[13], m1r[13];
    {
        bf16x8 bA = *(const bf16x8*)(w1sT + lr * 32 + lg * 8);
        bf16x8 bB = *(const bf16x8*)(w1sT + (16 + lr) * 32 + lg * 8);
        #pragma unroll
        for (int it = 0; it < 13; ++it) {
            int tt = wv + it * 4;
            if (tt < 49) {
                int u = (tt * 16 + lr) * 2 + lg;
                int su = u ^ ((u >> 3) & 7);
                bf16x8 af = *(const bf16x8*)(A1 + su * 8);
                f32x4 a0 = {0.0f, 0.0f, 0.0f, 0.0f};
                f32x4 a1acc = {0.0f, 0.0f, 0.0f, 0.0f};
                a0    = __builtin_amdgcn_mfma_f32_16x16x32_bf16(af, bA, a0, 0, 0, 0);
                a1acc = __builtin_amdgcn_mfma_f32_16x16x32_bf16(af, bB, a1acc, 0, 0, 0);
                m0r[it] = fmaxf(fmaxf(a0[0], a0[1]), fmaxf(a0[2], a0[3]));
                m1r[it] = fmaxf(fmaxf(a1acc[0], a1acc[1]), fmaxf(a1acc[2], a1acc[3]));
            }
        }
    }
    __syncthreads();

    for (int q = t; q < 1440; q += 256) ((uint4*)pl1p)[q] = uint4{0, 0, 0, 0};
    __syncthreads();

    {
        float bia0 = b1[lr], bia1 = b1[16 + lr];
        #pragma unroll
        for (int it = 0; it < 13; ++it) {
            int tt = wv + it * 4;
            if (tt < 49) {
                int base = (int)ptbl[tt * 4 + lg];
                pl1p[base + lr]      = f2bf(fmaxf(m0r[it] + bia0, 0.0f));
                pl1p[base + 16 + lr] = f2bf(fmaxf(m1r[it] + bia1, 0.0f));
            }
        }
    }
    __syncthreads();

    {
        bf16x8 bfr[9];
        #pragma unroll
        for (int s = 0; s < 9; ++s)
            bfr[s] = *(const bf16x8*)(W2gT + (wv * 16 + lr) * 296 + s * 32 + lg * 8);
        float bias2 = b2[wv * 16 + lr];

        #pragma unroll
        for (int pyp = 0; pyp < 7; ++pyp) {
            int py0 = pyp * 2;
            bf16x8 f[4][3];
            #pragma unroll
            for (int j = 0; j < 4; ++j)
                #pragma unroll
                for (int kx = 0; kx < 3; ++kx)
                    f[j][kx] = *(const bf16x8*)(pl1p + ((py0 + j) * 18 + (lr + kx)) * 40 + lg * 8);
            f32x4 acc0 = {bias2, bias2, bias2, bias2};
            f32x4 acc1 = acc0;
            #pragma unroll
            for (int ky = 0; ky < 3; ++ky)
                #pragma unroll
                for (int kx = 0; kx < 3; ++kx) {
                    acc0 = __builtin_amdgcn_mfma_f32_16x16x32_bf16(f[ky][kx],     bfr[ky * 3 + kx], acc0, 0, 0, 0);
                    acc1 = __builtin_amdgcn_mfma_f32_16x16x32_bf16(f[ky + 1][kx], bfr[ky * 3 + kx], acc1, 0, 0, 0);
                }
            float v0 = fmaxf(fmaxf(fmaxf(acc0[0], acc0[1]), fmaxf(acc1[0], acc1[1])), 0.0f);
            float v1 = fmaxf(fmaxf(fmaxf(acc0[2], acc0[3]), fmaxf(acc1[2], acc1[3])), 0.0f);
            int px0 = lg * 2, px1 = px0 + 1;
            size_t base = (size_t)i * 3136 + (size_t)(pyp * 7) * 64 + wv * 16 + lr;
            PL2[base + (size_t)px0 * 64] = f2bf(v0);
            if (px1 < 7) PL2[base + (size_t)px1 * 64] = f2bf(v1);
        }
    }
}

// Generic bf16 GEMM: C[M][N] = A[M][K] * BT[N][K]^T + bias, 64x64 tile, BK=64,
// 4 waves (2x2), double-buffered swizzled LDS (proven).
template<bool RELU, bool OUT_BF16>
__global__ __launch_bounds__(256) void gemm_bt_kernel(
        const ushort* __restrict__ A, const ushort* __restrict__ BT,
        const float* __restrict__ bias, void* __restrict__ Cout,
        int M, int N, int K) {
    __shared__ __align__(16) ushort lds[2][2][4096];   // [buf][A/B][64*64] bf16
    int t = threadIdx.x;
    int w = t >> 6, l = t & 63;
    int lr = l & 15, lc = l >> 4;
    int wm = w >> 1, wn = w & 1;
    int bm = blockIdx.x, bn = blockIdx.y;
    int NKt = K >> 6;

    const ushort* Ab = A + (size_t)bm * 64 * K;
    const ushort* Bb = BT + (size_t)bn * 64 * K;

    int r0 = t >> 3, s0 = t & 7;
    int c1i = t + 256;
    int r1 = c1i >> 3, s1 = c1i & 7;
    int d0 = r0 * 8 + (s0 ^ (r0 & 7));
    int d1 = r1 * 8 + (s1 ^ (r1 & 7));

    f32x4 acc[2][2] = {};

    uint4 tA0, tA1, tB0, tB1;
    #define GLOAD(kt) do { \
        tA0 = *(const uint4*)(Ab + (size_t)r0 * K + (kt) * 64 + s0 * 8); \
        tA1 = *(const uint4*)(Ab + (size_t)r1 * K + (kt) * 64 + s1 * 8); \
        tB0 = *(const uint4*)(Bb + (size_t)r0 * K + (kt) * 64 + s0 * 8); \
        tB1 = *(const uint4*)(Bb + (size_t)r1 * K + (kt) * 64 + s1 * 8); } while (0)
    #define LWRITE(bufi) do { \
        ((uint4*)lds[bufi][0])[d0] = tA0; ((uint4*)lds[bufi][0])[d1] = tA1; \
        ((uint4*)lds[bufi][1])[d0] = tB0; ((uint4*)lds[bufi][1])[d1] = tB1; } while (0)

    GLOAD(0); LWRITE(0);
    int buf = 0;
    for (int kt = 0; kt < NKt; ++kt) {
        __syncthreads();
        if (kt + 1 < NKt) GLOAD(kt + 1);
        const ushort* Al = lds[buf][0];
        const ushort* Bl = lds[buf][1];
        #pragma unroll
        for (int ks = 0; ks < 2; ++ks) {
            bf16x8 af[2], bg[2];
            #pragma unroll
            for (int mt = 0; mt < 2; ++mt) {
                int row = wm * 32 + mt * 16 + lr;
                int unit = row * 8 + ((ks * 4 + lc) ^ (row & 7));
                af[mt] = *(const bf16x8*)(Al + unit * 8);
            }
            #pragma unroll
            for (int nt = 0; nt < 2; ++nt) {
                int row = wn * 32 + nt * 16 + lr;
                int unit = row * 8 + ((ks * 4 + lc) ^ (row & 7));
                bg[nt] = *(const bf16x8*)(Bl + unit * 8);
            }
            #pragma unroll
            for (int mt = 0; mt < 2; ++mt)
                #pragma unroll
                for (int nt = 0; nt < 2; ++nt)
                    acc[mt][nt] = __builtin_amdgcn_mfma_f32_16x16x32_bf16(af[mt], bg[nt], acc[mt][nt], 0, 0, 0);
        }
        if (kt + 1 < NKt) LWRITE(buf ^ 1);
        buf ^= 1;
    }

    #pragma unroll
    for (int nt = 0; nt < 2; ++nt) {
        int gcol = bn * 64 + wn * 32 + nt * 16 + lr;
        float bv = bias[gcol];
        #pragma unroll
        for (int mt = 0; mt < 2; ++mt) {
            #pragma unroll
            for (int rg = 0; rg < 4; ++rg) {
                int grow = bm * 64 + wm * 32 + mt * 16 + lc * 4 + rg;
                float vv = acc[mt][nt][rg] + bv;
                if (RELU) vv = fmaxf(vv, 0.0f);
                if (OUT_BF16) ((ushort*)Cout)[(size_t)grow * N + gcol] = f2bf(vv);
                else          ((float*)Cout)[(size_t)grow * N + gcol] = vv;
            }
        }
    }
    #undef GLOAD
    #undef LWRITE
}

// ---------------- launch ----------------
extern "C" void kernel_launch(void* const* d_in, const int* in_sizes, int n_in,
                              void* d_out, int out_size, void* d_ws, size_t ws_size,
                              hipStream_t stream) {
    const float* x   = (const float*)d_in[0];
    const float* W1  = (const float*)d_in[1];
    const float* b1  = (const float*)d_in[2];
    const float* W2  = (const float*)d_in[3];
    const float* b2  = (const float*)d_in[4];
    const float* Wf  = (const float*)d_in[5];
    const float* bf  = (const float*)d_in[6];
    const float* Wp1 = (const float*)d_in[7];
    const float* bp1 = (const float*)d_in[8];
    const float* Wp2 = (const float*)d_in[9];
    const float* bp2 = (const float*)d_in[10];

    float* ws     = (float*)d_ws;
    float* P      = ws + P_OFF;
    uint32_t* NK  = (uint32_t*)(ws + NK_OFF);
    ushort* W2gT  = (ushort*)(ws + W2GT_OFF);
    ushort* WfB   = (ushort*)(ws + WFB_OFF);
    ushort* Wp1B  = (ushort*)(ws + WP1B_OFF);
    ushort* Wp2B  = (ushort*)(ws + WP2B_OFF);
    float* out    = (float*)d_out;

    prep_kernel<<<7658, 256, 0, stream>>>(P, NK, W2, W2gT, Wf, WfB,
                                          Wp1, Wp1B, Wp2, Wp2B);

    if (ws_size >= BATCH_FLOATS * 4ull) {
        // -------- batched: both views, padded bf16 AUG -----------------------
        ushort* AUGB8 = (ushort*)(ws + DATA_OFF);            // 8192*900 bf16
        ushort* PL28  = (ushort*)(ws + DATA_OFF + 3686400);  // 8192*3136 bf16
        ushort* H8    = (ushort*)(ws + DATA_OFF + 16531456); // 8192*512 bf16
        ushort* P18   = AUGB8;                               // alias

        augment_kernel<<<8192, 256, 0, stream>>>(x, P, NK, AUGB8, 0);
        conv12_kernel<<<8192, 256, 0, stream>>>(AUGB8, W1, b1, W2gT, b2, PL28);
        gemm_bt_kernel<false, true><<<dim3(128, 8), 256, 0, stream>>>(
            PL28, WfB, bf, H8, 8192, 512, 3136);
        gemm_bt_kernel<true, true><<<dim3(128, 8), 256, 0, stream>>>(
            H8, Wp1B, bp1, P18, 8192, 512, 512);
        gemm_bt_kernel<false, false><<<dim3(128, 2), 256, 0, stream>>>(
            P18, Wp2B, bp2, out, 8192, 128, 512);
    } else {
        // -------- per-view fallback (padded bf16 AUG) ------------------------
        ushort* AUGB = (ushort*)(ws + DATA_OFF);             // 4096*900 bf16
        ushort* PL2  = (ushort*)(ws + DATA_OFF + 1843200);   // 4096*3136 bf16
        ushort* Hb   = (ushort*)(ws + DATA_OFF + 8265728);   // 4096*512 bf16
        ushort* P1   = AUGB;

        for (int v = 0; v < 2; ++v) {
            augment_kernel<<<4096, 256, 0, stream>>>(x, P, NK, AUGB, v * 4096);
            conv12_kernel<<<4096, 256, 0, stream>>>(AUGB, W1, b1, W2gT, b2, PL2);
            gemm_bt_kernel<false, true><<<dim3(64, 8), 256, 0, stream>>>(
                PL2, WfB, bf, Hb, 4096, 512, 3136);
            gemm_bt_kernel<true, true><<<dim3(64, 8), 256, 0, stream>>>(
                Hb, Wp1B, bp1, P1, 4096, 512, 512);
            gemm_bt_kernel<false, false><<<dim3(64, 2), 256, 0, stream>>>(
                P1, Wp2B, bp2, out + (size_t)v * 4096 * 128, 4096, 128, 512);
        }
    }
}